// Round 7
// baseline (759.472 us; speedup 1.0000x reference)
//
#include <hip/hip_runtime.h>

// VQ-VAE vector quantize + losses, MI355X.
// T=8192 rows, N_E=16384 codes, D=32.
// R7: occupancy fix. R6 analysis: per-wave-tile time (188 cyc) == static
//     issue estimate -> SIMDs are latency-bound at 4 waves/SIMD, not
//     issue-bound (gfx94x VALUBusy formula misleading). So: NS1/RS2 doubled
//     -> 2048 blocks = 8 blocks/CU = 8 waves/SIMD (launch_bounds(256,8)),
//     and per-split operand slice drops to 32KB = L1-resident.
//     Everything else identical to R6 (bf16 hi/lo MFMA, C-bias, med3 top-2,
//     prefetch-1, exact fp32 refine of top-2, fused out+merge).

#define N_E 16384
#define ED 32
#define T 8192
#define NS1 32      // pass-1 code splits (512 codes each)
#define RS2 16      // pass-2 row splits  (512 rows each)

#define K2 288.53900817779268f    // 200 * log2(e)
#define NS2F -144.26950408889634f // -100 * log2(e)
#define LN2 0.6931471805599453f

typedef __attribute__((ext_vector_type(8))) short s16x8;
typedef __attribute__((ext_vector_type(4))) float f32x4;

__device__ __forceinline__ float fexp2(float x) { return __builtin_amdgcn_exp2f(x); }
__device__ __forceinline__ float flog2(float x) { return __builtin_amdgcn_logf(x); }
__device__ __forceinline__ float fmed3(float a, float b, float c) {
  return __builtin_amdgcn_fmed3f(a, b, c);
}

__device__ __forceinline__ unsigned short f2bf(float x) {
  unsigned u = __float_as_uint(x);
  unsigned r = (u + 0x7FFFu + ((u >> 16) & 1u)) >> 16;
  return (unsigned short)r;
}
__device__ __forceinline__ float bf2f(unsigned short h) {
  return __uint_as_float(((unsigned)h) << 16);
}

// exact fp32 dot of a streamed row with 8 resident float4s (by value)
__device__ __forceinline__ float dot32x(const float* __restrict__ p,
    float4 z0, float4 z1, float4 z2, float4 z3,
    float4 z4, float4 z5, float4 z6, float4 z7) {
  const float4* e = (const float4*)p;
  float a0 = 0.f, a1 = 0.f, a2 = 0.f, a3 = 0.f; float4 q;
  q = e[0]; a0 = fmaf(q.x, z0.x, a0); a0 = fmaf(q.y, z0.y, a0);
            a0 = fmaf(q.z, z0.z, a0); a0 = fmaf(q.w, z0.w, a0);
  q = e[1]; a1 = fmaf(q.x, z1.x, a1); a1 = fmaf(q.y, z1.y, a1);
            a1 = fmaf(q.z, z1.z, a1); a1 = fmaf(q.w, z1.w, a1);
  q = e[2]; a2 = fmaf(q.x, z2.x, a2); a2 = fmaf(q.y, z2.y, a2);
            a2 = fmaf(q.z, z2.z, a2); a2 = fmaf(q.w, z2.w, a2);
  q = e[3]; a3 = fmaf(q.x, z3.x, a3); a3 = fmaf(q.y, z3.y, a3);
            a3 = fmaf(q.z, z3.z, a3); a3 = fmaf(q.w, z3.w, a3);
  q = e[4]; a0 = fmaf(q.x, z4.x, a0); a0 = fmaf(q.y, z4.y, a0);
            a0 = fmaf(q.z, z4.z, a0); a0 = fmaf(q.w, z4.w, a0);
  q = e[5]; a1 = fmaf(q.x, z5.x, a1); a1 = fmaf(q.y, z5.y, a1);
            a1 = fmaf(q.z, z5.z, a1); a1 = fmaf(q.w, z5.w, a1);
  q = e[6]; a2 = fmaf(q.x, z6.x, a2); a2 = fmaf(q.y, z6.y, a2);
            a2 = fmaf(q.z, z6.z, a2); a2 = fmaf(q.w, z6.w, a2);
  q = e[7]; a3 = fmaf(q.x, z7.x, a3); a3 = fmaf(q.y, z7.y, a3);
            a3 = fmaf(q.z, z7.z, a3); a3 = fmaf(q.w, z7.w, a3);
  return (a0 + a1) + (a2 + a3);
}

// split 8 floats (scaled by sc) into hi/lo bf16 groups and store interleaved
__device__ __forceinline__ void split_store(short* __restrict__ base,
    size_t row, int g, float4 va, float4 vb, float sc) {
  float f[8] = { va.x * sc, va.y * sc, va.z * sc, va.w * sc,
                 vb.x * sc, vb.y * sc, vb.z * sc, vb.w * sc };
  s16x8 H, L;
#pragma unroll
  for (int e = 0; e < 8; ++e) {
    unsigned short h = f2bf(f[e]);
    H[e] = (short)h;
    L[e] = (short)f2bf(f[e] - bf2f(h));
  }
  s16x8* p = (s16x8*)base + row * 8 + g * 2;
  p[0] = H; p[1] = L;
}

// --- prep: normalize embedding rows; fp32 + interleaved bf16 hi/lo + ses2 ---
__global__ __launch_bounds__(256) void k_prep_emb(const float* __restrict__ emb,
    float* __restrict__ embn, float* __restrict__ ses2, short* __restrict__ ehl) {
  int n = blockIdx.x * 256 + threadIdx.x;
  const float4* r4 = (const float4*)(emb + (size_t)n * ED);
  float4 v[8]; float s = 0.f;
#pragma unroll
  for (int j = 0; j < 8; ++j) {
    v[j] = r4[j];
    s = fmaf(v[j].x, v[j].x, s); s = fmaf(v[j].y, v[j].y, s);
    s = fmaf(v[j].z, v[j].z, s); s = fmaf(v[j].w, v[j].w, s);
  }
  float inv = 1.0f / fmaxf(sqrtf(s), 1e-12f);
  float s2 = 0.f;
  float4* o4 = (float4*)(embn + (size_t)n * ED);
#pragma unroll
  for (int j = 0; j < 8; ++j) {
    float4 w; w.x = v[j].x * inv; w.y = v[j].y * inv;
    w.z = v[j].z * inv; w.w = v[j].w * inv;
    o4[j] = w; v[j] = w;
    s2 = fmaf(w.x, w.x, s2); s2 = fmaf(w.y, w.y, s2);
    s2 = fmaf(w.z, w.z, s2); s2 = fmaf(w.w, w.w, s2);
  }
  ses2[n] = NS2F * s2;
#pragma unroll
  for (int g = 0; g < 4; ++g)
    split_store(ehl, (size_t)n, g, v[2 * g], v[2 * g + 1], 1.0f);
}

// --- prep: transpose+normalize z; fp32 zf + K2-prescaled bf16 hi/lo + a02 ---
__global__ __launch_bounds__(256) void k_prep_z(const float* __restrict__ z,
    float* __restrict__ zf, float* __restrict__ a02, short* __restrict__ zhl) {
  int t = blockIdx.x * 256 + threadIdx.x;
  int b = t >> 8, hw = t & 255;
  const float* base = z + (size_t)b * (ED * 256) + hw;
  float4 v[8]; float s = 0.f;
#pragma unroll
  for (int j = 0; j < 8; ++j) {
    float4 w;
    w.x = base[(4 * j + 0) * 256]; w.y = base[(4 * j + 1) * 256];
    w.z = base[(4 * j + 2) * 256]; w.w = base[(4 * j + 3) * 256];
    v[j] = w;
    s = fmaf(w.x, w.x, s); s = fmaf(w.y, w.y, s);
    s = fmaf(w.z, w.z, s); s = fmaf(w.w, w.w, s);
  }
  float inv = 1.0f / fmaxf(sqrtf(s), 1e-12f);
  float s2 = 0.f;
  float4* o4 = (float4*)(zf + (size_t)t * ED);
#pragma unroll
  for (int j = 0; j < 8; ++j) {
    float4 w; w.x = v[j].x * inv; w.y = v[j].y * inv;
    w.z = v[j].z * inv; w.w = v[j].w * inv;
    o4[j] = w; v[j] = w;
    s2 = fmaf(w.x, w.x, s2); s2 = fmaf(w.y, w.y, s2);
    s2 = fmaf(w.z, w.z, s2); s2 = fmaf(w.w, w.w, s2);
  }
  a02[t] = NS2F * s2;
#pragma unroll
  for (int g = 0; g < 4; ++g)
    split_store(zhl, (size_t)t, g, v[2 * g], v[2 * g + 1], K2);
}

// --- pass 1: wave owns 32 rows, sweeps a 512-code split in 16-code tiles.
//     acc C-init = a02+80; fb = acc + ses2[code]. med3 top-2 + biased Z. ---
__global__ __launch_bounds__(256, 8) void k_pass1(
    const short* __restrict__ ehl, const short* __restrict__ zhl,
    const float* __restrict__ ses2, const float* __restrict__ a02,
    float* __restrict__ pm1, float* __restrict__ pm2, float* __restrict__ pZ,
    int* __restrict__ pi1, int* __restrict__ pi2) {
  const int lane = threadIdx.x & 63, wv = threadIdx.x >> 6;
  const int q = lane >> 4, c = lane & 15;
  const int rowbase = blockIdx.x * 128 + wv * 32;
  const int nb0 = blockIdx.y * (N_E / NS1);
  const int NT = (N_E / NS1) / 16;  // 32

  const s16x8* zg = (const s16x8*)zhl;
  const int aidx = (rowbase + c) * 8 + q * 2;
  s16x8 ah0 = zg[aidx], al0 = zg[aidx + 1];
  s16x8 ah1 = zg[aidx + 128], al1 = zg[aidx + 129];   // +16 rows

  f32x4 bias0, bias1;
#pragma unroll
  for (int r = 0; r < 4; ++r) {
    bias0[r] = a02[rowbase + q * 4 + r] + 80.0f;
    bias1[r] = a02[rowbase + 16 + q * 4 + r] + 80.0f;
  }

  float m1[8], m2[8], Zs[8]; int i1[8], i2[8];
#pragma unroll
  for (int k = 0; k < 8; ++k) {
    m1[k] = -1e30f; m2[k] = -1e30f; Zs[k] = 0.f;
    i1[k] = nb0 + c; i2[k] = nb0 + c;
  }

  const s16x8* eg = (const s16x8*)ehl;
  const int bbase = (nb0 + c) * 8 + q * 2;
  s16x8 bh = eg[bbase], bl = eg[bbase + 1];
  float sesc = ses2[nb0 + c];

  for (int tile = 0; tile < NT; ++tile) {
    const int nx = (tile + 1 < NT) ? tile + 1 : tile;     // uniform
    const int nidx = bbase + nx * 128;
    s16x8 nh = eg[nidx], nl = eg[nidx + 1];               // prefetch
    float nses = ses2[nb0 + nx * 16 + c];

    f32x4 acc0 = __builtin_amdgcn_mfma_f32_16x16x32_bf16(ah0, bh, bias0, 0, 0, 0);
    f32x4 acc1 = __builtin_amdgcn_mfma_f32_16x16x32_bf16(ah1, bh, bias1, 0, 0, 0);
    acc0 = __builtin_amdgcn_mfma_f32_16x16x32_bf16(al0, bh, acc0, 0, 0, 0);
    acc1 = __builtin_amdgcn_mfma_f32_16x16x32_bf16(al1, bh, acc1, 0, 0, 0);
    acc0 = __builtin_amdgcn_mfma_f32_16x16x32_bf16(ah0, bl, acc0, 0, 0, 0);
    acc1 = __builtin_amdgcn_mfma_f32_16x16x32_bf16(ah1, bl, acc1, 0, 0, 0);

    const int vn = nb0 + tile * 16 + c;
#pragma unroll
    for (int g = 0; g < 2; ++g) {
#pragma unroll
      for (int r = 0; r < 4; ++r) {
        const int k = g * 4 + r;
        float fb = ((g == 0) ? acc0[r] : acc1[r]) + sesc;
        bool g1 = fb > m1[k];
        bool g2 = fb > m2[k];
        i2[k] = g1 ? i1[k] : (g2 ? vn : i2[k]);
        m2[k] = fmed3(fb, m1[k], m2[k]);   // 2nd-max of {m1,m2,fb}
        i1[k] = g1 ? vn : i1[k];
        m1[k] = fmaxf(m1[k], fb);
        Zs[k] += fexp2(fb);
      }
    }
    bh = nh; bl = nl; sesc = nses;
  }

  // reduce across the 16 cols within each quad
#pragma unroll
  for (int d = 1; d < 16; d <<= 1) {
#pragma unroll
    for (int k = 0; k < 8; ++k) {
      float om1 = __shfl_xor(m1[k], d);
      float om2 = __shfl_xor(m2[k], d);
      float oZ = __shfl_xor(Zs[k], d);
      int oi1 = __shfl_xor(i1[k], d);
      int oi2 = __shfl_xor(i2[k], d);
      bool c1 = om1 > m1[k];
      float lm = c1 ? m1[k] : om1;
      int li = c1 ? i1[k] : oi1;
      float nm1 = c1 ? om1 : m1[k];
      int ni1 = c1 ? oi1 : i1[k];
      bool cb = om2 > m2[k];
      float mm2 = cb ? om2 : m2[k];
      int mi2 = cb ? oi2 : i2[k];
      bool c3 = mm2 > lm;
      m1[k] = nm1; i1[k] = ni1;
      m2[k] = c3 ? mm2 : lm;
      i2[k] = c3 ? mi2 : li;
      Zs[k] += oZ;
    }
  }

#pragma unroll
  for (int k = 0; k < 8; ++k) {
    if (c == k) {
      const int g = k >> 2, r = k & 3;
      const int t = rowbase + g * 16 + q * 4 + r;
      const int p = blockIdx.y * T + t;
      pm1[p] = m1[k]; pm2[p] = m2[k]; pZ[p] = Zs[k];
      pi1[p] = i1[k]; pi2[p] = i2[k];
    }
  }
}

// --- merge: combine split partials; exact fp32 re-compare of candidates;
//     lse2, c2 = a02 - lse2, vq sum-of-squares, straight-through output. ---
__global__ __launch_bounds__(256) void k_merge(
    const float* __restrict__ pm1, const float* __restrict__ pm2,
    const float* __restrict__ pZ, const int* __restrict__ pi1,
    const int* __restrict__ pi2, const float* __restrict__ zf,
    const float* __restrict__ embn, const float* __restrict__ ses2,
    const float* __restrict__ a02, float* __restrict__ c2,
    int* __restrict__ idxo, float* __restrict__ scal, float* __restrict__ out) {
  const int t = blockIdx.x * 256 + threadIdx.x;
  float m1 = -1e30f, m2 = -1e30f, Z = 0.f;
  int i1 = 0, i2 = 0;
  for (int s = 0; s < NS1; ++s) {
    const int p = s * T + t;
    float sm1 = pm1[p], sm2 = pm2[p];
    int si1 = pi1[p], si2 = pi2[p];
    Z += pZ[p];
    bool c1 = sm1 > m1;
    float lm = c1 ? m1 : sm1;
    int li = c1 ? i1 : si1;
    float nm1 = c1 ? sm1 : m1;
    int ni1 = c1 ? si1 : i1;
    bool cb = sm2 > m2;
    float mm2 = cb ? sm2 : m2;
    int mi2 = cb ? si2 : i2;
    bool c3 = mm2 > lm;
    m1 = nm1; i1 = ni1;
    m2 = c3 ? mm2 : lm;
    i2 = c3 ? mi2 : li;
  }
  const float a02t = a02[t];
  const float lse2 = flog2(Z) - 80.0f;
  c2[t] = a02t - lse2;

  const float4* zr4 = (const float4*)(zf + (size_t)t * ED);
  float4 z0 = zr4[0], z1 = zr4[1], z2 = zr4[2], z3 = zr4[3];
  float4 z4 = zr4[4], z5 = zr4[5], z6 = zr4[6], z7 = zr4[7];
  float d1 = dot32x(embn + (size_t)i1 * ED, z0, z1, z2, z3, z4, z5, z6, z7);
  float d2 = dot32x(embn + (size_t)i2 * ED, z0, z1, z2, z3, z4, z5, z6, z7);
  float fb1 = fmaf(K2, d1, a02t + ses2[i1]);
  float fb2 = fmaf(K2, d2, a02t + ses2[i2]);
  int bi = (fb2 > fb1 || (fb2 == fb1 && i2 < i1)) ? i2 : i1;
  idxo[t] = bi;

  // vq sum-of-squares + straight-through output (out = zb + (z_q - zb))
  const int b = t >> 8, hw = t & 255;
  float* ob = out + (size_t)b * (ED * 256) + hw;
  float ss = 0.f;
  const float4* e4 = (const float4*)(embn + (size_t)bi * ED);
#pragma unroll
  for (int j = 0; j < 8; ++j) {
    float4 qv = e4[j];
    float4 zv = (j == 0) ? z0 : (j == 1) ? z1 : (j == 2) ? z2 : (j == 3) ? z3
              : (j == 4) ? z4 : (j == 5) ? z5 : (j == 6) ? z6 : z7;
    float df;
    df = qv.x - zv.x; ss = fmaf(df, df, ss); ob[(4 * j + 0) * 256] = zv.x + (qv.x - zv.x);
    df = qv.y - zv.y; ss = fmaf(df, df, ss); ob[(4 * j + 1) * 256] = zv.y + (qv.y - zv.y);
    df = qv.z - zv.z; ss = fmaf(df, df, ss); ob[(4 * j + 2) * 256] = zv.z + (qv.z - zv.z);
    df = qv.w - zv.w; ss = fmaf(df, df, ss); ob[(4 * j + 3) * 256] = zv.w + (qv.w - zv.w);
  }
  __shared__ float red[256];
  red[threadIdx.x] = ss;
  __syncthreads();
  for (int st = 128; st > 0; st >>= 1) {
    if (threadIdx.x < st) red[threadIdx.x] += red[threadIdx.x + st];
    __syncthreads();
  }
  if (threadIdx.x == 0) atomicAdd(&scal[1], red[0]);
}

// --- pass 2: wave owns 32 codes, sweeps a 512-row split in 16-row tiles.
//     acc C-init = ses2[code]; dl = acc + c2[t] = fb - lse2. ---
__global__ __launch_bounds__(256, 8) void k_pass2(
    const short* __restrict__ ehl, const short* __restrict__ zhl,
    const float* __restrict__ ses2, const float* __restrict__ c2,
    float* __restrict__ avg, float* __restrict__ scal) {
  const int lane = threadIdx.x & 63, wv = threadIdx.x >> 6;
  const int q = lane >> 4, c = lane & 15;
  const int cbase = blockIdx.x * 128 + wv * 32;
  const int tb0 = blockIdx.y * (T / RS2);
  const int NT = (T / RS2) / 16;  // 32

  const s16x8* eg = (const s16x8*)ehl;
  const int aidx = (cbase + c) * 8 + q * 2;
  s16x8 ah0 = eg[aidx], al0 = eg[aidx + 1];
  s16x8 ah1 = eg[aidx + 128], al1 = eg[aidx + 129];

  f32x4 sg0, sg1;
#pragma unroll
  for (int r = 0; r < 4; ++r) {
    sg0[r] = ses2[cbase + q * 4 + r];
    sg1[r] = ses2[cbase + 16 + q * 4 + r];
  }

  float accP[8], accE[8];
#pragma unroll
  for (int k = 0; k < 8; ++k) { accP[k] = 0.f; accE[k] = 0.f; }

  const s16x8* zg = (const s16x8*)zhl;
  const int bbase = (tb0 + c) * 8 + q * 2;
  s16x8 bh = zg[bbase], bl = zg[bbase + 1];
  float cc = c2[tb0 + c];

  for (int tile = 0; tile < NT; ++tile) {
    const int nx = (tile + 1 < NT) ? tile + 1 : tile;
    const int nidx = bbase + nx * 128;
    s16x8 nh = zg[nidx], nl = zg[nidx + 1];               // prefetch
    float ncc = c2[tb0 + nx * 16 + c];

    f32x4 acc0 = __builtin_amdgcn_mfma_f32_16x16x32_bf16(ah0, bh, sg0, 0, 0, 0);
    f32x4 acc1 = __builtin_amdgcn_mfma_f32_16x16x32_bf16(ah1, bh, sg1, 0, 0, 0);
    acc0 = __builtin_amdgcn_mfma_f32_16x16x32_bf16(al0, bh, acc0, 0, 0, 0);
    acc1 = __builtin_amdgcn_mfma_f32_16x16x32_bf16(al1, bh, acc1, 0, 0, 0);
    acc0 = __builtin_amdgcn_mfma_f32_16x16x32_bf16(ah0, bl, acc0, 0, 0, 0);
    acc1 = __builtin_amdgcn_mfma_f32_16x16x32_bf16(ah1, bl, acc1, 0, 0, 0);

#pragma unroll
    for (int g = 0; g < 2; ++g) {
#pragma unroll
      for (int r = 0; r < 4; ++r) {
        const int k = g * 4 + r;
        float dl = ((g == 0) ? acc0[r] : acc1[r]) + cc;  // fb - lse2 (<=0)
        float p = fexp2(dl);                              // underflow -> 0
        accP[k] += p;
        accE[k] = fmaf(p, dl, accE[k]);
      }
    }
    bh = nh; bl = nl; cc = ncc;
  }

  float etot = 0.f;
#pragma unroll
  for (int k = 0; k < 8; ++k) etot += accE[k];

#pragma unroll
  for (int d = 1; d < 16; d <<= 1) {
#pragma unroll
    for (int k = 0; k < 8; ++k) accP[k] += __shfl_xor(accP[k], d);
  }
#pragma unroll
  for (int k = 0; k < 8; ++k) {
    if (c == k) {
      const int g = k >> 2, r = k & 3;
      atomicAdd(&avg[cbase + g * 16 + q * 4 + r], accP[k]);
    }
  }
  __shared__ float red[256];
  red[threadIdx.x] = etot;
  __syncthreads();
  for (int st = 128; st > 0; st >>= 1) {
    if (threadIdx.x < st) red[threadIdx.x] += red[threadIdx.x + st];
    __syncthreads();
  }
  if (threadIdx.x == 0) atomicAdd(&scal[0], red[0]);
}

// --- final scalars. ---
__global__ __launch_bounds__(256) void k_final(const float* __restrict__ avg,
    const float* __restrict__ scal, float* __restrict__ out) {
  float s = 0.f;
  for (int i = threadIdx.x; i < N_E; i += 256) {
    float a = avg[i] * (1.0f / T);
    s += a * (flog2(a + 1e-5f) * LN2);
  }
  __shared__ float red[256];
  red[threadIdx.x] = s;
  __syncthreads();
  for (int st = 128; st > 0; st >>= 1) {
    if (threadIdx.x < st) red[threadIdx.x] += red[threadIdx.x + st];
    __syncthreads();
  }
  if (threadIdx.x == 0) {
    float avg_entropy = -red[0];
    float sample_entropy = -(scal[0] * LN2) * (1.0f / T);
    float vq = scal[1] * (1.0f / (T * ED));
    out[T * ED + 0] = vq;
    out[T * ED + 1] = 0.25f * vq;
    out[T * ED + 2] = 0.1f * (sample_entropy - avg_entropy);
  }
}

extern "C" void kernel_launch(void* const* d_in, const int* in_sizes, int n_in,
                              void* d_out, int out_size, void* d_ws, size_t ws_size,
                              hipStream_t stream) {
  const float* z = (const float*)d_in[0];
  const float* emb = (const float*)d_in[1];
  float* out = (float*)d_out;
  float* w = (float*)d_ws;

  float* embn = w;                          // 524288 f
  float* ses2 = embn + 524288;              // 16384
  float* zf   = ses2 + 16384;               // 262144
  float* a02  = zf + 262144;                // 8192
  short* ehl  = (short*)(a02 + 8192);       // 1048576 sh (524288 f)
  short* zhl  = ehl + 1048576;              // 524288 sh  (262144 f)
  float* pm1  = (float*)(zhl + 524288);     // NS1*T = 262144 f
  float* pm2  = pm1 + NS1 * T;              // 262144
  float* pZ   = pm2 + NS1 * T;              // 262144
  int*   pi1  = (int*)(pZ + NS1 * T);       // 262144
  int*   pi2  = pi1 + NS1 * T;              // 262144
  float* c2   = (float*)(pi2 + NS1 * T);    // 8192
  int*   idxo = (int*)(c2 + 8192);          // 8192
  float* avg  = (float*)(idxo + 8192);      // 16384
  float* scal = avg + 16384;                // 2     (~11.7 MB total)

  hipMemsetAsync(avg, 0, (16384 + 2) * sizeof(float), stream);

  k_prep_emb<<<64, 256, 0, stream>>>(emb, embn, ses2, ehl);
  k_prep_z<<<32, 256, 0, stream>>>(z, zf, a02, zhl);
  k_pass1<<<dim3(T / 128, NS1), 256, 0, stream>>>(ehl, zhl, ses2, a02,
                                                  pm1, pm2, pZ, pi1, pi2);
  k_merge<<<32, 256, 0, stream>>>(pm1, pm2, pZ, pi1, pi2, zf, embn, ses2, a02,
                                  c2, idxo, scal, out);
  k_pass2<<<dim3(N_E / 128, RS2), 256, 0, stream>>>(ehl, zhl, ses2, c2, avg, scal);
  k_final<<<1, 256, 0, stream>>>(avg, scal, out);
}

// Round 8
// 266.470 us; speedup vs baseline: 2.8501x; 2.8501x over previous
//
#include <hip/hip_runtime.h>

// VQ-VAE vector quantize + losses, MI355X.
// T=8192 rows, N_E=16384 codes, D=32.
// R8: R7's grid (NS1=32/RS2=16 -> 2048 blocks = 8 blocks/CU) but launch
//     bounds back to (256,4): R7's (256,8) capped VGPR at 64 and spilled
//     (VGPR=32, FETCH=WRITE=1.2GB, 570us). R6's VGPR=52 <= 64 means HW
//     reaches 8 waves/SIMD by itself when the grid supplies the blocks.
//     Everything else identical to R6/R7 (bf16 hi/lo MFMA, C-bias, med3
//     top-2, prefetch-1, exact fp32 refine, fused out+merge).

#define N_E 16384
#define ED 32
#define T 8192
#define NS1 32      // pass-1 code splits (512 codes each)
#define RS2 16      // pass-2 row splits  (512 rows each)

#define K2 288.53900817779268f    // 200 * log2(e)
#define NS2F -144.26950408889634f // -100 * log2(e)
#define LN2 0.6931471805599453f

typedef __attribute__((ext_vector_type(8))) short s16x8;
typedef __attribute__((ext_vector_type(4))) float f32x4;

__device__ __forceinline__ float fexp2(float x) { return __builtin_amdgcn_exp2f(x); }
__device__ __forceinline__ float flog2(float x) { return __builtin_amdgcn_logf(x); }
__device__ __forceinline__ float fmed3(float a, float b, float c) {
  return __builtin_amdgcn_fmed3f(a, b, c);
}

__device__ __forceinline__ unsigned short f2bf(float x) {
  unsigned u = __float_as_uint(x);
  unsigned r = (u + 0x7FFFu + ((u >> 16) & 1u)) >> 16;
  return (unsigned short)r;
}
__device__ __forceinline__ float bf2f(unsigned short h) {
  return __uint_as_float(((unsigned)h) << 16);
}

// exact fp32 dot of a streamed row with 8 resident float4s (by value)
__device__ __forceinline__ float dot32x(const float* __restrict__ p,
    float4 z0, float4 z1, float4 z2, float4 z3,
    float4 z4, float4 z5, float4 z6, float4 z7) {
  const float4* e = (const float4*)p;
  float a0 = 0.f, a1 = 0.f, a2 = 0.f, a3 = 0.f; float4 q;
  q = e[0]; a0 = fmaf(q.x, z0.x, a0); a0 = fmaf(q.y, z0.y, a0);
            a0 = fmaf(q.z, z0.z, a0); a0 = fmaf(q.w, z0.w, a0);
  q = e[1]; a1 = fmaf(q.x, z1.x, a1); a1 = fmaf(q.y, z1.y, a1);
            a1 = fmaf(q.z, z1.z, a1); a1 = fmaf(q.w, z1.w, a1);
  q = e[2]; a2 = fmaf(q.x, z2.x, a2); a2 = fmaf(q.y, z2.y, a2);
            a2 = fmaf(q.z, z2.z, a2); a2 = fmaf(q.w, z2.w, a2);
  q = e[3]; a3 = fmaf(q.x, z3.x, a3); a3 = fmaf(q.y, z3.y, a3);
            a3 = fmaf(q.z, z3.z, a3); a3 = fmaf(q.w, z3.w, a3);
  q = e[4]; a0 = fmaf(q.x, z4.x, a0); a0 = fmaf(q.y, z4.y, a0);
            a0 = fmaf(q.z, z4.z, a0); a0 = fmaf(q.w, z4.w, a0);
  q = e[5]; a1 = fmaf(q.x, z5.x, a1); a1 = fmaf(q.y, z5.y, a1);
            a1 = fmaf(q.z, z5.z, a1); a1 = fmaf(q.w, z5.w, a1);
  q = e[6]; a2 = fmaf(q.x, z6.x, a2); a2 = fmaf(q.y, z6.y, a2);
            a2 = fmaf(q.z, z6.z, a2); a2 = fmaf(q.w, z6.w, a2);
  q = e[7]; a3 = fmaf(q.x, z7.x, a3); a3 = fmaf(q.y, z7.y, a3);
            a3 = fmaf(q.z, z7.z, a3); a3 = fmaf(q.w, z7.w, a3);
  return (a0 + a1) + (a2 + a3);
}

// split 8 floats (scaled by sc) into hi/lo bf16 groups and store interleaved
__device__ __forceinline__ void split_store(short* __restrict__ base,
    size_t row, int g, float4 va, float4 vb, float sc) {
  float f[8] = { va.x * sc, va.y * sc, va.z * sc, va.w * sc,
                 vb.x * sc, vb.y * sc, vb.z * sc, vb.w * sc };
  s16x8 H, L;
#pragma unroll
  for (int e = 0; e < 8; ++e) {
    unsigned short h = f2bf(f[e]);
    H[e] = (short)h;
    L[e] = (short)f2bf(f[e] - bf2f(h));
  }
  s16x8* p = (s16x8*)base + row * 8 + g * 2;
  p[0] = H; p[1] = L;
}

// --- prep: normalize embedding rows; fp32 + interleaved bf16 hi/lo + ses2 ---
__global__ __launch_bounds__(256) void k_prep_emb(const float* __restrict__ emb,
    float* __restrict__ embn, float* __restrict__ ses2, short* __restrict__ ehl) {
  int n = blockIdx.x * 256 + threadIdx.x;
  const float4* r4 = (const float4*)(emb + (size_t)n * ED);
  float4 v[8]; float s = 0.f;
#pragma unroll
  for (int j = 0; j < 8; ++j) {
    v[j] = r4[j];
    s = fmaf(v[j].x, v[j].x, s); s = fmaf(v[j].y, v[j].y, s);
    s = fmaf(v[j].z, v[j].z, s); s = fmaf(v[j].w, v[j].w, s);
  }
  float inv = 1.0f / fmaxf(sqrtf(s), 1e-12f);
  float s2 = 0.f;
  float4* o4 = (float4*)(embn + (size_t)n * ED);
#pragma unroll
  for (int j = 0; j < 8; ++j) {
    float4 w; w.x = v[j].x * inv; w.y = v[j].y * inv;
    w.z = v[j].z * inv; w.w = v[j].w * inv;
    o4[j] = w; v[j] = w;
    s2 = fmaf(w.x, w.x, s2); s2 = fmaf(w.y, w.y, s2);
    s2 = fmaf(w.z, w.z, s2); s2 = fmaf(w.w, w.w, s2);
  }
  ses2[n] = NS2F * s2;
#pragma unroll
  for (int g = 0; g < 4; ++g)
    split_store(ehl, (size_t)n, g, v[2 * g], v[2 * g + 1], 1.0f);
}

// --- prep: transpose+normalize z; fp32 zf + K2-prescaled bf16 hi/lo + a02 ---
__global__ __launch_bounds__(256) void k_prep_z(const float* __restrict__ z,
    float* __restrict__ zf, float* __restrict__ a02, short* __restrict__ zhl) {
  int t = blockIdx.x * 256 + threadIdx.x;
  int b = t >> 8, hw = t & 255;
  const float* base = z + (size_t)b * (ED * 256) + hw;
  float4 v[8]; float s = 0.f;
#pragma unroll
  for (int j = 0; j < 8; ++j) {
    float4 w;
    w.x = base[(4 * j + 0) * 256]; w.y = base[(4 * j + 1) * 256];
    w.z = base[(4 * j + 2) * 256]; w.w = base[(4 * j + 3) * 256];
    v[j] = w;
    s = fmaf(w.x, w.x, s); s = fmaf(w.y, w.y, s);
    s = fmaf(w.z, w.z, s); s = fmaf(w.w, w.w, s);
  }
  float inv = 1.0f / fmaxf(sqrtf(s), 1e-12f);
  float s2 = 0.f;
  float4* o4 = (float4*)(zf + (size_t)t * ED);
#pragma unroll
  for (int j = 0; j < 8; ++j) {
    float4 w; w.x = v[j].x * inv; w.y = v[j].y * inv;
    w.z = v[j].z * inv; w.w = v[j].w * inv;
    o4[j] = w; v[j] = w;
    s2 = fmaf(w.x, w.x, s2); s2 = fmaf(w.y, w.y, s2);
    s2 = fmaf(w.z, w.z, s2); s2 = fmaf(w.w, w.w, s2);
  }
  a02[t] = NS2F * s2;
#pragma unroll
  for (int g = 0; g < 4; ++g)
    split_store(zhl, (size_t)t, g, v[2 * g], v[2 * g + 1], K2);
}

// --- pass 1: wave owns 32 rows, sweeps a 512-code split in 16-code tiles.
//     acc C-init = a02+80; fb = acc + ses2[code]. med3 top-2 + biased Z. ---
__global__ __launch_bounds__(256, 4) void k_pass1(
    const short* __restrict__ ehl, const short* __restrict__ zhl,
    const float* __restrict__ ses2, const float* __restrict__ a02,
    float* __restrict__ pm1, float* __restrict__ pm2, float* __restrict__ pZ,
    int* __restrict__ pi1, int* __restrict__ pi2) {
  const int lane = threadIdx.x & 63, wv = threadIdx.x >> 6;
  const int q = lane >> 4, c = lane & 15;
  const int rowbase = blockIdx.x * 128 + wv * 32;
  const int nb0 = blockIdx.y * (N_E / NS1);
  const int NT = (N_E / NS1) / 16;  // 32

  const s16x8* zg = (const s16x8*)zhl;
  const int aidx = (rowbase + c) * 8 + q * 2;
  s16x8 ah0 = zg[aidx], al0 = zg[aidx + 1];
  s16x8 ah1 = zg[aidx + 128], al1 = zg[aidx + 129];   // +16 rows

  f32x4 bias0, bias1;
#pragma unroll
  for (int r = 0; r < 4; ++r) {
    bias0[r] = a02[rowbase + q * 4 + r] + 80.0f;
    bias1[r] = a02[rowbase + 16 + q * 4 + r] + 80.0f;
  }

  float m1[8], m2[8], Zs[8]; int i1[8], i2[8];
#pragma unroll
  for (int k = 0; k < 8; ++k) {
    m1[k] = -1e30f; m2[k] = -1e30f; Zs[k] = 0.f;
    i1[k] = nb0 + c; i2[k] = nb0 + c;
  }

  const s16x8* eg = (const s16x8*)ehl;
  const int bbase = (nb0 + c) * 8 + q * 2;
  s16x8 bh = eg[bbase], bl = eg[bbase + 1];
  float sesc = ses2[nb0 + c];

  for (int tile = 0; tile < NT; ++tile) {
    const int nx = (tile + 1 < NT) ? tile + 1 : tile;     // uniform
    const int nidx = bbase + nx * 128;
    s16x8 nh = eg[nidx], nl = eg[nidx + 1];               // prefetch
    float nses = ses2[nb0 + nx * 16 + c];

    f32x4 acc0 = __builtin_amdgcn_mfma_f32_16x16x32_bf16(ah0, bh, bias0, 0, 0, 0);
    f32x4 acc1 = __builtin_amdgcn_mfma_f32_16x16x32_bf16(ah1, bh, bias1, 0, 0, 0);
    acc0 = __builtin_amdgcn_mfma_f32_16x16x32_bf16(al0, bh, acc0, 0, 0, 0);
    acc1 = __builtin_amdgcn_mfma_f32_16x16x32_bf16(al1, bh, acc1, 0, 0, 0);
    acc0 = __builtin_amdgcn_mfma_f32_16x16x32_bf16(ah0, bl, acc0, 0, 0, 0);
    acc1 = __builtin_amdgcn_mfma_f32_16x16x32_bf16(ah1, bl, acc1, 0, 0, 0);

    const int vn = nb0 + tile * 16 + c;
#pragma unroll
    for (int g = 0; g < 2; ++g) {
#pragma unroll
      for (int r = 0; r < 4; ++r) {
        const int k = g * 4 + r;
        float fb = ((g == 0) ? acc0[r] : acc1[r]) + sesc;
        bool g1 = fb > m1[k];
        bool g2 = fb > m2[k];
        i2[k] = g1 ? i1[k] : (g2 ? vn : i2[k]);
        m2[k] = fmed3(fb, m1[k], m2[k]);   // 2nd-max of {m1,m2,fb}
        i1[k] = g1 ? vn : i1[k];
        m1[k] = fmaxf(m1[k], fb);
        Zs[k] += fexp2(fb);
      }
    }
    bh = nh; bl = nl; sesc = nses;
  }

  // reduce across the 16 cols within each quad
#pragma unroll
  for (int d = 1; d < 16; d <<= 1) {
#pragma unroll
    for (int k = 0; k < 8; ++k) {
      float om1 = __shfl_xor(m1[k], d);
      float om2 = __shfl_xor(m2[k], d);
      float oZ = __shfl_xor(Zs[k], d);
      int oi1 = __shfl_xor(i1[k], d);
      int oi2 = __shfl_xor(i2[k], d);
      bool c1 = om1 > m1[k];
      float lm = c1 ? m1[k] : om1;
      int li = c1 ? i1[k] : oi1;
      float nm1 = c1 ? om1 : m1[k];
      int ni1 = c1 ? oi1 : i1[k];
      bool cb = om2 > m2[k];
      float mm2 = cb ? om2 : m2[k];
      int mi2 = cb ? oi2 : i2[k];
      bool c3 = mm2 > lm;
      m1[k] = nm1; i1[k] = ni1;
      m2[k] = c3 ? mm2 : lm;
      i2[k] = c3 ? mi2 : li;
      Zs[k] += oZ;
    }
  }

#pragma unroll
  for (int k = 0; k < 8; ++k) {
    if (c == k) {
      const int g = k >> 2, r = k & 3;
      const int t = rowbase + g * 16 + q * 4 + r;
      const int p = blockIdx.y * T + t;
      pm1[p] = m1[k]; pm2[p] = m2[k]; pZ[p] = Zs[k];
      pi1[p] = i1[k]; pi2[p] = i2[k];
    }
  }
}

// --- merge: combine split partials; exact fp32 re-compare of candidates;
//     lse2, c2 = a02 - lse2, vq sum-of-squares, straight-through output. ---
__global__ __launch_bounds__(256) void k_merge(
    const float* __restrict__ pm1, const float* __restrict__ pm2,
    const float* __restrict__ pZ, const int* __restrict__ pi1,
    const int* __restrict__ pi2, const float* __restrict__ zf,
    const float* __restrict__ embn, const float* __restrict__ ses2,
    const float* __restrict__ a02, float* __restrict__ c2,
    int* __restrict__ idxo, float* __restrict__ scal, float* __restrict__ out) {
  const int t = blockIdx.x * 256 + threadIdx.x;
  float m1 = -1e30f, m2 = -1e30f, Z = 0.f;
  int i1 = 0, i2 = 0;
  for (int s = 0; s < NS1; ++s) {
    const int p = s * T + t;
    float sm1 = pm1[p], sm2 = pm2[p];
    int si1 = pi1[p], si2 = pi2[p];
    Z += pZ[p];
    bool c1 = sm1 > m1;
    float lm = c1 ? m1 : sm1;
    int li = c1 ? i1 : si1;
    float nm1 = c1 ? sm1 : m1;
    int ni1 = c1 ? si1 : i1;
    bool cb = sm2 > m2;
    float mm2 = cb ? sm2 : m2;
    int mi2 = cb ? si2 : i2;
    bool c3 = mm2 > lm;
    m1 = nm1; i1 = ni1;
    m2 = c3 ? mm2 : lm;
    i2 = c3 ? mi2 : li;
  }
  const float a02t = a02[t];
  const float lse2 = flog2(Z) - 80.0f;
  c2[t] = a02t - lse2;

  const float4* zr4 = (const float4*)(zf + (size_t)t * ED);
  float4 z0 = zr4[0], z1 = zr4[1], z2 = zr4[2], z3 = zr4[3];
  float4 z4 = zr4[4], z5 = zr4[5], z6 = zr4[6], z7 = zr4[7];
  float d1 = dot32x(embn + (size_t)i1 * ED, z0, z1, z2, z3, z4, z5, z6, z7);
  float d2 = dot32x(embn + (size_t)i2 * ED, z0, z1, z2, z3, z4, z5, z6, z7);
  float fb1 = fmaf(K2, d1, a02t + ses2[i1]);
  float fb2 = fmaf(K2, d2, a02t + ses2[i2]);
  int bi = (fb2 > fb1 || (fb2 == fb1 && i2 < i1)) ? i2 : i1;
  idxo[t] = bi;

  // vq sum-of-squares + straight-through output (out = zb + (z_q - zb))
  const int b = t >> 8, hw = t & 255;
  float* ob = out + (size_t)b * (ED * 256) + hw;
  float ss = 0.f;
  const float4* e4 = (const float4*)(embn + (size_t)bi * ED);
#pragma unroll
  for (int j = 0; j < 8; ++j) {
    float4 qv = e4[j];
    float4 zv = (j == 0) ? z0 : (j == 1) ? z1 : (j == 2) ? z2 : (j == 3) ? z3
              : (j == 4) ? z4 : (j == 5) ? z5 : (j == 6) ? z6 : z7;
    float df;
    df = qv.x - zv.x; ss = fmaf(df, df, ss); ob[(4 * j + 0) * 256] = zv.x + (qv.x - zv.x);
    df = qv.y - zv.y; ss = fmaf(df, df, ss); ob[(4 * j + 1) * 256] = zv.y + (qv.y - zv.y);
    df = qv.z - zv.z; ss = fmaf(df, df, ss); ob[(4 * j + 2) * 256] = zv.z + (qv.z - zv.z);
    df = qv.w - zv.w; ss = fmaf(df, df, ss); ob[(4 * j + 3) * 256] = zv.w + (qv.w - zv.w);
  }
  __shared__ float red[256];
  red[threadIdx.x] = ss;
  __syncthreads();
  for (int st = 128; st > 0; st >>= 1) {
    if (threadIdx.x < st) red[threadIdx.x] += red[threadIdx.x + st];
    __syncthreads();
  }
  if (threadIdx.x == 0) atomicAdd(&scal[1], red[0]);
}

// --- pass 2: wave owns 32 codes, sweeps a 512-row split in 16-row tiles.
//     acc C-init = ses2[code]; dl = acc + c2[t] = fb - lse2. ---
__global__ __launch_bounds__(256, 4) void k_pass2(
    const short* __restrict__ ehl, const short* __restrict__ zhl,
    const float* __restrict__ ses2, const float* __restrict__ c2,
    float* __restrict__ avg, float* __restrict__ scal) {
  const int lane = threadIdx.x & 63, wv = threadIdx.x >> 6;
  const int q = lane >> 4, c = lane & 15;
  const int cbase = blockIdx.x * 128 + wv * 32;
  const int tb0 = blockIdx.y * (T / RS2);
  const int NT = (T / RS2) / 16;  // 32

  const s16x8* eg = (const s16x8*)ehl;
  const int aidx = (cbase + c) * 8 + q * 2;
  s16x8 ah0 = eg[aidx], al0 = eg[aidx + 1];
  s16x8 ah1 = eg[aidx + 128], al1 = eg[aidx + 129];

  f32x4 sg0, sg1;
#pragma unroll
  for (int r = 0; r < 4; ++r) {
    sg0[r] = ses2[cbase + q * 4 + r];
    sg1[r] = ses2[cbase + 16 + q * 4 + r];
  }

  float accP[8], accE[8];
#pragma unroll
  for (int k = 0; k < 8; ++k) { accP[k] = 0.f; accE[k] = 0.f; }

  const s16x8* zg = (const s16x8*)zhl;
  const int bbase = (tb0 + c) * 8 + q * 2;
  s16x8 bh = zg[bbase], bl = zg[bbase + 1];
  float cc = c2[tb0 + c];

  for (int tile = 0; tile < NT; ++tile) {
    const int nx = (tile + 1 < NT) ? tile + 1 : tile;
    const int nidx = bbase + nx * 128;
    s16x8 nh = zg[nidx], nl = zg[nidx + 1];               // prefetch
    float ncc = c2[tb0 + nx * 16 + c];

    f32x4 acc0 = __builtin_amdgcn_mfma_f32_16x16x32_bf16(ah0, bh, sg0, 0, 0, 0);
    f32x4 acc1 = __builtin_amdgcn_mfma_f32_16x16x32_bf16(ah1, bh, sg1, 0, 0, 0);
    acc0 = __builtin_amdgcn_mfma_f32_16x16x32_bf16(al0, bh, acc0, 0, 0, 0);
    acc1 = __builtin_amdgcn_mfma_f32_16x16x32_bf16(al1, bh, acc1, 0, 0, 0);
    acc0 = __builtin_amdgcn_mfma_f32_16x16x32_bf16(ah0, bl, acc0, 0, 0, 0);
    acc1 = __builtin_amdgcn_mfma_f32_16x16x32_bf16(ah1, bl, acc1, 0, 0, 0);

#pragma unroll
    for (int g = 0; g < 2; ++g) {
#pragma unroll
      for (int r = 0; r < 4; ++r) {
        const int k = g * 4 + r;
        float dl = ((g == 0) ? acc0[r] : acc1[r]) + cc;  // fb - lse2 (<=0)
        float p = fexp2(dl);                              // underflow -> 0
        accP[k] += p;
        accE[k] = fmaf(p, dl, accE[k]);
      }
    }
    bh = nh; bl = nl; cc = ncc;
  }

  float etot = 0.f;
#pragma unroll
  for (int k = 0; k < 8; ++k) etot += accE[k];

#pragma unroll
  for (int d = 1; d < 16; d <<= 1) {
#pragma unroll
    for (int k = 0; k < 8; ++k) accP[k] += __shfl_xor(accP[k], d);
  }
#pragma unroll
  for (int k = 0; k < 8; ++k) {
    if (c == k) {
      const int g = k >> 2, r = k & 3;
      atomicAdd(&avg[cbase + g * 16 + q * 4 + r], accP[k]);
    }
  }
  __shared__ float red[256];
  red[threadIdx.x] = etot;
  __syncthreads();
  for (int st = 128; st > 0; st >>= 1) {
    if (threadIdx.x < st) red[threadIdx.x] += red[threadIdx.x + st];
    __syncthreads();
  }
  if (threadIdx.x == 0) atomicAdd(&scal[0], red[0]);
}

// --- final scalars. ---
__global__ __launch_bounds__(256) void k_final(const float* __restrict__ avg,
    const float* __restrict__ scal, float* __restrict__ out) {
  float s = 0.f;
  for (int i = threadIdx.x; i < N_E; i += 256) {
    float a = avg[i] * (1.0f / T);
    s += a * (flog2(a + 1e-5f) * LN2);
  }
  __shared__ float red[256];
  red[threadIdx.x] = s;
  __syncthreads();
  for (int st = 128; st > 0; st >>= 1) {
    if (threadIdx.x < st) red[threadIdx.x] += red[threadIdx.x + st];
    __syncthreads();
  }
  if (threadIdx.x == 0) {
    float avg_entropy = -red[0];
    float sample_entropy = -(scal[0] * LN2) * (1.0f / T);
    float vq = scal[1] * (1.0f / (T * ED));
    out[T * ED + 0] = vq;
    out[T * ED + 1] = 0.25f * vq;
    out[T * ED + 2] = 0.1f * (sample_entropy - avg_entropy);
  }
}

extern "C" void kernel_launch(void* const* d_in, const int* in_sizes, int n_in,
                              void* d_out, int out_size, void* d_ws, size_t ws_size,
                              hipStream_t stream) {
  const float* z = (const float*)d_in[0];
  const float* emb = (const float*)d_in[1];
  float* out = (float*)d_out;
  float* w = (float*)d_ws;

  float* embn = w;                          // 524288 f
  float* ses2 = embn + 524288;              // 16384
  float* zf   = ses2 + 16384;               // 262144
  float* a02  = zf + 262144;                // 8192
  short* ehl  = (short*)(a02 + 8192);       // 1048576 sh (524288 f)
  short* zhl  = ehl + 1048576;              // 524288 sh  (262144 f)
  float* pm1  = (float*)(zhl + 524288);     // NS1*T = 262144 f
  float* pm2  = pm1 + NS1 * T;              // 262144
  float* pZ   = pm2 + NS1 * T;              // 262144
  int*   pi1  = (int*)(pZ + NS1 * T);       // 262144
  int*   pi2  = pi1 + NS1 * T;              // 262144
  float* c2   = (float*)(pi2 + NS1 * T);    // 8192
  int*   idxo = (int*)(c2 + 8192);          // 8192
  float* avg  = (float*)(idxo + 8192);      // 16384
  float* scal = avg + 16384;                // 2     (~11.7 MB total)

  hipMemsetAsync(avg, 0, (16384 + 2) * sizeof(float), stream);

  k_prep_emb<<<64, 256, 0, stream>>>(emb, embn, ses2, ehl);
  k_prep_z<<<32, 256, 0, stream>>>(z, zf, a02, zhl);
  k_pass1<<<dim3(T / 128, NS1), 256, 0, stream>>>(ehl, zhl, ses2, a02,
                                                  pm1, pm2, pZ, pi1, pi2);
  k_merge<<<32, 256, 0, stream>>>(pm1, pm2, pZ, pi1, pi2, zf, embn, ses2, a02,
                                  c2, idxo, scal, out);
  k_pass2<<<dim3(N_E / 128, RS2), 256, 0, stream>>>(ehl, zhl, ses2, c2, avg, scal);
  k_final<<<1, 256, 0, stream>>>(avg, scal, out);
}

// Round 9
// 245.563 us; speedup vs baseline: 3.0928x; 1.0851x over previous
//
#include <hip/hip_runtime.h>

// VQ-VAE vector quantize + losses, MI355X.
// T=8192 rows, N_E=16384 codes, D=32.
// R9: R6 base (NS1=16/RS2=8, bounds (256,4) -- measured best, 235us) with
//     pair-unrolled inner loops + pair-depth prefetch (4x16B loads in
//     flight vs 2). R8 evidence: pass2 VALUBusy=22% -> both sweeps are
//     in-flight-load limited; R7/R8 split-doubling discredited.

#define N_E 16384
#define ED 32
#define T 8192
#define NS1 16      // pass-1 code splits (1024 codes each)
#define RS2 8       // pass-2 row splits  (1024 rows each)

#define K2 288.53900817779268f    // 200 * log2(e)
#define NS2F -144.26950408889634f // -100 * log2(e)
#define LN2 0.6931471805599453f

typedef __attribute__((ext_vector_type(8))) short s16x8;
typedef __attribute__((ext_vector_type(4))) float f32x4;

__device__ __forceinline__ float fexp2(float x) { return __builtin_amdgcn_exp2f(x); }
__device__ __forceinline__ float flog2(float x) { return __builtin_amdgcn_logf(x); }
__device__ __forceinline__ float fmed3(float a, float b, float c) {
  return __builtin_amdgcn_fmed3f(a, b, c);
}

__device__ __forceinline__ unsigned short f2bf(float x) {
  unsigned u = __float_as_uint(x);
  unsigned r = (u + 0x7FFFu + ((u >> 16) & 1u)) >> 16;
  return (unsigned short)r;
}
__device__ __forceinline__ float bf2f(unsigned short h) {
  return __uint_as_float(((unsigned)h) << 16);
}

// exact fp32 dot of a streamed row with 8 resident float4s (by value)
__device__ __forceinline__ float dot32x(const float* __restrict__ p,
    float4 z0, float4 z1, float4 z2, float4 z3,
    float4 z4, float4 z5, float4 z6, float4 z7) {
  const float4* e = (const float4*)p;
  float a0 = 0.f, a1 = 0.f, a2 = 0.f, a3 = 0.f; float4 q;
  q = e[0]; a0 = fmaf(q.x, z0.x, a0); a0 = fmaf(q.y, z0.y, a0);
            a0 = fmaf(q.z, z0.z, a0); a0 = fmaf(q.w, z0.w, a0);
  q = e[1]; a1 = fmaf(q.x, z1.x, a1); a1 = fmaf(q.y, z1.y, a1);
            a1 = fmaf(q.z, z1.z, a1); a1 = fmaf(q.w, z1.w, a1);
  q = e[2]; a2 = fmaf(q.x, z2.x, a2); a2 = fmaf(q.y, z2.y, a2);
            a2 = fmaf(q.z, z2.z, a2); a2 = fmaf(q.w, z2.w, a2);
  q = e[3]; a3 = fmaf(q.x, z3.x, a3); a3 = fmaf(q.y, z3.y, a3);
            a3 = fmaf(q.z, z3.z, a3); a3 = fmaf(q.w, z3.w, a3);
  q = e[4]; a0 = fmaf(q.x, z4.x, a0); a0 = fmaf(q.y, z4.y, a0);
            a0 = fmaf(q.z, z4.z, a0); a0 = fmaf(q.w, z4.w, a0);
  q = e[5]; a1 = fmaf(q.x, z5.x, a1); a1 = fmaf(q.y, z5.y, a1);
            a1 = fmaf(q.z, z5.z, a1); a1 = fmaf(q.w, z5.w, a1);
  q = e[6]; a2 = fmaf(q.x, z6.x, a2); a2 = fmaf(q.y, z6.y, a2);
            a2 = fmaf(q.z, z6.z, a2); a2 = fmaf(q.w, z6.w, a2);
  q = e[7]; a3 = fmaf(q.x, z7.x, a3); a3 = fmaf(q.y, z7.y, a3);
            a3 = fmaf(q.z, z7.z, a3); a3 = fmaf(q.w, z7.w, a3);
  return (a0 + a1) + (a2 + a3);
}

// split 8 floats (scaled by sc) into hi/lo bf16 groups and store interleaved
__device__ __forceinline__ void split_store(short* __restrict__ base,
    size_t row, int g, float4 va, float4 vb, float sc) {
  float f[8] = { va.x * sc, va.y * sc, va.z * sc, va.w * sc,
                 vb.x * sc, vb.y * sc, vb.z * sc, vb.w * sc };
  s16x8 H, L;
#pragma unroll
  for (int e = 0; e < 8; ++e) {
    unsigned short h = f2bf(f[e]);
    H[e] = (short)h;
    L[e] = (short)f2bf(f[e] - bf2f(h));
  }
  s16x8* p = (s16x8*)base + row * 8 + g * 2;
  p[0] = H; p[1] = L;
}

// --- prep: normalize embedding rows; fp32 + interleaved bf16 hi/lo + ses2 ---
__global__ __launch_bounds__(256) void k_prep_emb(const float* __restrict__ emb,
    float* __restrict__ embn, float* __restrict__ ses2, short* __restrict__ ehl) {
  int n = blockIdx.x * 256 + threadIdx.x;
  const float4* r4 = (const float4*)(emb + (size_t)n * ED);
  float4 v[8]; float s = 0.f;
#pragma unroll
  for (int j = 0; j < 8; ++j) {
    v[j] = r4[j];
    s = fmaf(v[j].x, v[j].x, s); s = fmaf(v[j].y, v[j].y, s);
    s = fmaf(v[j].z, v[j].z, s); s = fmaf(v[j].w, v[j].w, s);
  }
  float inv = 1.0f / fmaxf(sqrtf(s), 1e-12f);
  float s2 = 0.f;
  float4* o4 = (float4*)(embn + (size_t)n * ED);
#pragma unroll
  for (int j = 0; j < 8; ++j) {
    float4 w; w.x = v[j].x * inv; w.y = v[j].y * inv;
    w.z = v[j].z * inv; w.w = v[j].w * inv;
    o4[j] = w; v[j] = w;
    s2 = fmaf(w.x, w.x, s2); s2 = fmaf(w.y, w.y, s2);
    s2 = fmaf(w.z, w.z, s2); s2 = fmaf(w.w, w.w, s2);
  }
  ses2[n] = NS2F * s2;
#pragma unroll
  for (int g = 0; g < 4; ++g)
    split_store(ehl, (size_t)n, g, v[2 * g], v[2 * g + 1], 1.0f);
}

// --- prep: transpose+normalize z; fp32 zf + K2-prescaled bf16 hi/lo + a02 ---
__global__ __launch_bounds__(256) void k_prep_z(const float* __restrict__ z,
    float* __restrict__ zf, float* __restrict__ a02, short* __restrict__ zhl) {
  int t = blockIdx.x * 256 + threadIdx.x;
  int b = t >> 8, hw = t & 255;
  const float* base = z + (size_t)b * (ED * 256) + hw;
  float4 v[8]; float s = 0.f;
#pragma unroll
  for (int j = 0; j < 8; ++j) {
    float4 w;
    w.x = base[(4 * j + 0) * 256]; w.y = base[(4 * j + 1) * 256];
    w.z = base[(4 * j + 2) * 256]; w.w = base[(4 * j + 3) * 256];
    v[j] = w;
    s = fmaf(w.x, w.x, s); s = fmaf(w.y, w.y, s);
    s = fmaf(w.z, w.z, s); s = fmaf(w.w, w.w, s);
  }
  float inv = 1.0f / fmaxf(sqrtf(s), 1e-12f);
  float s2 = 0.f;
  float4* o4 = (float4*)(zf + (size_t)t * ED);
#pragma unroll
  for (int j = 0; j < 8; ++j) {
    float4 w; w.x = v[j].x * inv; w.y = v[j].y * inv;
    w.z = v[j].z * inv; w.w = v[j].w * inv;
    o4[j] = w; v[j] = w;
    s2 = fmaf(w.x, w.x, s2); s2 = fmaf(w.y, w.y, s2);
    s2 = fmaf(w.z, w.z, s2); s2 = fmaf(w.w, w.w, s2);
  }
  a02[t] = NS2F * s2;
#pragma unroll
  for (int g = 0; g < 4; ++g)
    split_store(zhl, (size_t)t, g, v[2 * g], v[2 * g + 1], K2);
}

// top-2 update for one 4-reg acc group against state slots k0..k0+3
#define UPD1(ACC, SES, VN, K0)                                              \
  _Pragma("unroll")                                                         \
  for (int r = 0; r < 4; ++r) {                                             \
    const int k = (K0) + r;                                                 \
    float fb = (ACC)[r] + (SES);                                            \
    bool g1 = fb > m1[k];                                                   \
    bool g2 = fb > m2[k];                                                   \
    i2[k] = g1 ? i1[k] : (g2 ? (VN) : i2[k]);                               \
    m2[k] = fmed3(fb, m1[k], m2[k]);                                        \
    i1[k] = g1 ? (VN) : i1[k];                                              \
    m1[k] = fmaxf(m1[k], fb);                                               \
    Zs[k] += fexp2(fb);                                                     \
  }

// --- pass 1: wave owns 32 rows, sweeps a 1024-code split in PAIRS of
//     16-code tiles; next pair fully prefetched (4x16B + 2 scalars in
//     flight). acc C-init = a02+80; fb = acc + ses2[code]. ---
__global__ __launch_bounds__(256, 4) void k_pass1(
    const short* __restrict__ ehl, const short* __restrict__ zhl,
    const float* __restrict__ ses2, const float* __restrict__ a02,
    float* __restrict__ pm1, float* __restrict__ pm2, float* __restrict__ pZ,
    int* __restrict__ pi1, int* __restrict__ pi2) {
  const int lane = threadIdx.x & 63, wv = threadIdx.x >> 6;
  const int q = lane >> 4, c = lane & 15;
  const int rowbase = blockIdx.x * 128 + wv * 32;
  const int nb0 = blockIdx.y * (N_E / NS1);
  const int NP = (N_E / NS1) / 32;  // 32 pairs

  const s16x8* zg = (const s16x8*)zhl;
  const int aidx = (rowbase + c) * 8 + q * 2;
  s16x8 ah0 = zg[aidx], al0 = zg[aidx + 1];
  s16x8 ah1 = zg[aidx + 128], al1 = zg[aidx + 129];   // +16 rows

  f32x4 bias0, bias1;
#pragma unroll
  for (int r = 0; r < 4; ++r) {
    bias0[r] = a02[rowbase + q * 4 + r] + 80.0f;
    bias1[r] = a02[rowbase + 16 + q * 4 + r] + 80.0f;
  }

  float m1[8], m2[8], Zs[8]; int i1[8], i2[8];
#pragma unroll
  for (int k = 0; k < 8; ++k) {
    m1[k] = -1e30f; m2[k] = -1e30f; Zs[k] = 0.f;
    i1[k] = nb0 + c; i2[k] = nb0 + c;
  }

  const s16x8* eg = (const s16x8*)ehl;
  const int bbase = (nb0 + c) * 8 + q * 2;
  s16x8 bh0 = eg[bbase],       bl0 = eg[bbase + 1];
  s16x8 bh1 = eg[bbase + 128], bl1 = eg[bbase + 129];
  float ses0 = ses2[nb0 + c], ses1 = ses2[nb0 + 16 + c];

  for (int pr = 0; pr < NP; ++pr) {
    const int nxt = (pr + 1 < NP) ? pr + 1 : pr;        // uniform
    const int ni = bbase + nxt * 256;
    s16x8 ph0 = eg[ni],       pl0 = eg[ni + 1];          // prefetch pair
    s16x8 ph1 = eg[ni + 128], pl1 = eg[ni + 129];
    float ps0 = ses2[nb0 + nxt * 32 + c];
    float ps1 = ses2[nb0 + nxt * 32 + 16 + c];

    // tile A (codes pr*32 .. +16)
    f32x4 acc0 = __builtin_amdgcn_mfma_f32_16x16x32_bf16(ah0, bh0, bias0, 0, 0, 0);
    f32x4 acc1 = __builtin_amdgcn_mfma_f32_16x16x32_bf16(ah1, bh0, bias1, 0, 0, 0);
    acc0 = __builtin_amdgcn_mfma_f32_16x16x32_bf16(al0, bh0, acc0, 0, 0, 0);
    acc1 = __builtin_amdgcn_mfma_f32_16x16x32_bf16(al1, bh0, acc1, 0, 0, 0);
    acc0 = __builtin_amdgcn_mfma_f32_16x16x32_bf16(ah0, bl0, acc0, 0, 0, 0);
    acc1 = __builtin_amdgcn_mfma_f32_16x16x32_bf16(ah1, bl0, acc1, 0, 0, 0);
    {
      const int vn = nb0 + pr * 32 + c;
      UPD1(acc0, ses0, vn, 0)
      UPD1(acc1, ses0, vn, 4)
    }

    // tile B (codes pr*32+16 .. +32)
    acc0 = __builtin_amdgcn_mfma_f32_16x16x32_bf16(ah0, bh1, bias0, 0, 0, 0);
    acc1 = __builtin_amdgcn_mfma_f32_16x16x32_bf16(ah1, bh1, bias1, 0, 0, 0);
    acc0 = __builtin_amdgcn_mfma_f32_16x16x32_bf16(al0, bh1, acc0, 0, 0, 0);
    acc1 = __builtin_amdgcn_mfma_f32_16x16x32_bf16(al1, bh1, acc1, 0, 0, 0);
    acc0 = __builtin_amdgcn_mfma_f32_16x16x32_bf16(ah0, bl1, acc0, 0, 0, 0);
    acc1 = __builtin_amdgcn_mfma_f32_16x16x32_bf16(ah1, bl1, acc1, 0, 0, 0);
    {
      const int vn = nb0 + pr * 32 + 16 + c;
      UPD1(acc0, ses1, vn, 0)
      UPD1(acc1, ses1, vn, 4)
    }

    bh0 = ph0; bl0 = pl0; bh1 = ph1; bl1 = pl1;
    ses0 = ps0; ses1 = ps1;
  }

  // reduce across the 16 cols within each quad
#pragma unroll
  for (int d = 1; d < 16; d <<= 1) {
#pragma unroll
    for (int k = 0; k < 8; ++k) {
      float om1 = __shfl_xor(m1[k], d);
      float om2 = __shfl_xor(m2[k], d);
      float oZ = __shfl_xor(Zs[k], d);
      int oi1 = __shfl_xor(i1[k], d);
      int oi2 = __shfl_xor(i2[k], d);
      bool c1 = om1 > m1[k];
      float lm = c1 ? m1[k] : om1;
      int li = c1 ? i1[k] : oi1;
      float nm1 = c1 ? om1 : m1[k];
      int ni1 = c1 ? oi1 : i1[k];
      bool cb = om2 > m2[k];
      float mm2 = cb ? om2 : m2[k];
      int mi2 = cb ? oi2 : i2[k];
      bool c3 = mm2 > lm;
      m1[k] = nm1; i1[k] = ni1;
      m2[k] = c3 ? mm2 : lm;
      i2[k] = c3 ? mi2 : li;
      Zs[k] += oZ;
    }
  }

#pragma unroll
  for (int k = 0; k < 8; ++k) {
    if (c == k) {
      const int g = k >> 2, r = k & 3;
      const int t = rowbase + g * 16 + q * 4 + r;
      const int p = blockIdx.y * T + t;
      pm1[p] = m1[k]; pm2[p] = m2[k]; pZ[p] = Zs[k];
      pi1[p] = i1[k]; pi2[p] = i2[k];
    }
  }
}

// --- merge: combine split partials; exact fp32 re-compare of candidates;
//     lse2, c2 = a02 - lse2, vq sum-of-squares, straight-through output. ---
__global__ __launch_bounds__(256) void k_merge(
    const float* __restrict__ pm1, const float* __restrict__ pm2,
    const float* __restrict__ pZ, const int* __restrict__ pi1,
    const int* __restrict__ pi2, const float* __restrict__ zf,
    const float* __restrict__ embn, const float* __restrict__ ses2,
    const float* __restrict__ a02, float* __restrict__ c2,
    int* __restrict__ idxo, float* __restrict__ scal, float* __restrict__ out) {
  const int t = blockIdx.x * 256 + threadIdx.x;
  float m1 = -1e30f, m2 = -1e30f, Z = 0.f;
  int i1 = 0, i2 = 0;
  for (int s = 0; s < NS1; ++s) {
    const int p = s * T + t;
    float sm1 = pm1[p], sm2 = pm2[p];
    int si1 = pi1[p], si2 = pi2[p];
    Z += pZ[p];
    bool c1 = sm1 > m1;
    float lm = c1 ? m1 : sm1;
    int li = c1 ? i1 : si1;
    float nm1 = c1 ? sm1 : m1;
    int ni1 = c1 ? si1 : i1;
    bool cb = sm2 > m2;
    float mm2 = cb ? sm2 : m2;
    int mi2 = cb ? si2 : i2;
    bool c3 = mm2 > lm;
    m1 = nm1; i1 = ni1;
    m2 = c3 ? mm2 : lm;
    i2 = c3 ? mi2 : li;
  }
  const float a02t = a02[t];
  const float lse2 = flog2(Z) - 80.0f;
  c2[t] = a02t - lse2;

  const float4* zr4 = (const float4*)(zf + (size_t)t * ED);
  float4 z0 = zr4[0], z1 = zr4[1], z2 = zr4[2], z3 = zr4[3];
  float4 z4 = zr4[4], z5 = zr4[5], z6 = zr4[6], z7 = zr4[7];
  float d1 = dot32x(embn + (size_t)i1 * ED, z0, z1, z2, z3, z4, z5, z6, z7);
  float d2 = dot32x(embn + (size_t)i2 * ED, z0, z1, z2, z3, z4, z5, z6, z7);
  float fb1 = fmaf(K2, d1, a02t + ses2[i1]);
  float fb2 = fmaf(K2, d2, a02t + ses2[i2]);
  int bi = (fb2 > fb1 || (fb2 == fb1 && i2 < i1)) ? i2 : i1;
  idxo[t] = bi;

  // vq sum-of-squares + straight-through output (out = zb + (z_q - zb))
  const int b = t >> 8, hw = t & 255;
  float* ob = out + (size_t)b * (ED * 256) + hw;
  float ss = 0.f;
  const float4* e4 = (const float4*)(embn + (size_t)bi * ED);
#pragma unroll
  for (int j = 0; j < 8; ++j) {
    float4 qv = e4[j];
    float4 zv = (j == 0) ? z0 : (j == 1) ? z1 : (j == 2) ? z2 : (j == 3) ? z3
              : (j == 4) ? z4 : (j == 5) ? z5 : (j == 6) ? z6 : z7;
    float df;
    df = qv.x - zv.x; ss = fmaf(df, df, ss); ob[(4 * j + 0) * 256] = zv.x + (qv.x - zv.x);
    df = qv.y - zv.y; ss = fmaf(df, df, ss); ob[(4 * j + 1) * 256] = zv.y + (qv.y - zv.y);
    df = qv.z - zv.z; ss = fmaf(df, df, ss); ob[(4 * j + 2) * 256] = zv.z + (qv.z - zv.z);
    df = qv.w - zv.w; ss = fmaf(df, df, ss); ob[(4 * j + 3) * 256] = zv.w + (qv.w - zv.w);
  }
  __shared__ float red[256];
  red[threadIdx.x] = ss;
  __syncthreads();
  for (int st = 128; st > 0; st >>= 1) {
    if (threadIdx.x < st) red[threadIdx.x] += red[threadIdx.x + st];
    __syncthreads();
  }
  if (threadIdx.x == 0) atomicAdd(&scal[1], red[0]);
}

#define UPD2(ACC, CC, K0)                                                   \
  _Pragma("unroll")                                                         \
  for (int r = 0; r < 4; ++r) {                                             \
    const int k = (K0) + r;                                                 \
    float dl = (ACC)[r] + (CC);                                             \
    float p = fexp2(dl);                                                    \
    accP[k] += p;                                                           \
    accE[k] = fmaf(p, dl, accE[k]);                                         \
  }

// --- pass 2: wave owns 32 codes, sweeps a 1024-row split in PAIRS of
//     16-row tiles; next pair fully prefetched. acc C-init = ses2[code];
//     dl = acc + c2[t] = fb - lse2 (<=0), exp2 underflows to 0. ---
__global__ __launch_bounds__(256, 4) void k_pass2(
    const short* __restrict__ ehl, const short* __restrict__ zhl,
    const float* __restrict__ ses2, const float* __restrict__ c2,
    float* __restrict__ avg, float* __restrict__ scal) {
  const int lane = threadIdx.x & 63, wv = threadIdx.x >> 6;
  const int q = lane >> 4, c = lane & 15;
  const int cbase = blockIdx.x * 128 + wv * 32;
  const int tb0 = blockIdx.y * (T / RS2);
  const int NP = (T / RS2) / 32;  // 32 pairs

  const s16x8* eg = (const s16x8*)ehl;
  const int aidx = (cbase + c) * 8 + q * 2;
  s16x8 ah0 = eg[aidx], al0 = eg[aidx + 1];
  s16x8 ah1 = eg[aidx + 128], al1 = eg[aidx + 129];

  f32x4 sg0, sg1;
#pragma unroll
  for (int r = 0; r < 4; ++r) {
    sg0[r] = ses2[cbase + q * 4 + r];
    sg1[r] = ses2[cbase + 16 + q * 4 + r];
  }

  float accP[8], accE[8];
#pragma unroll
  for (int k = 0; k < 8; ++k) { accP[k] = 0.f; accE[k] = 0.f; }

  const s16x8* zg = (const s16x8*)zhl;
  const int bbase = (tb0 + c) * 8 + q * 2;
  s16x8 bh0 = zg[bbase],       bl0 = zg[bbase + 1];
  s16x8 bh1 = zg[bbase + 128], bl1 = zg[bbase + 129];
  float cc0 = c2[tb0 + c], cc1 = c2[tb0 + 16 + c];

  for (int pr = 0; pr < NP; ++pr) {
    const int nxt = (pr + 1 < NP) ? pr + 1 : pr;
    const int ni = bbase + nxt * 256;
    s16x8 ph0 = zg[ni],       pl0 = zg[ni + 1];          // prefetch pair
    s16x8 ph1 = zg[ni + 128], pl1 = zg[ni + 129];
    float pc0 = c2[tb0 + nxt * 32 + c];
    float pc1 = c2[tb0 + nxt * 32 + 16 + c];

    // tile A (rows pr*32 .. +16)
    f32x4 acc0 = __builtin_amdgcn_mfma_f32_16x16x32_bf16(ah0, bh0, sg0, 0, 0, 0);
    f32x4 acc1 = __builtin_amdgcn_mfma_f32_16x16x32_bf16(ah1, bh0, sg1, 0, 0, 0);
    acc0 = __builtin_amdgcn_mfma_f32_16x16x32_bf16(al0, bh0, acc0, 0, 0, 0);
    acc1 = __builtin_amdgcn_mfma_f32_16x16x32_bf16(al1, bh0, acc1, 0, 0, 0);
    acc0 = __builtin_amdgcn_mfma_f32_16x16x32_bf16(ah0, bl0, acc0, 0, 0, 0);
    acc1 = __builtin_amdgcn_mfma_f32_16x16x32_bf16(ah1, bl0, acc1, 0, 0, 0);
    UPD2(acc0, cc0, 0)
    UPD2(acc1, cc0, 4)

    // tile B (rows pr*32+16 .. +32)
    acc0 = __builtin_amdgcn_mfma_f32_16x16x32_bf16(ah0, bh1, sg0, 0, 0, 0);
    acc1 = __builtin_amdgcn_mfma_f32_16x16x32_bf16(ah1, bh1, sg1, 0, 0, 0);
    acc0 = __builtin_amdgcn_mfma_f32_16x16x32_bf16(al0, bh1, acc0, 0, 0, 0);
    acc1 = __builtin_amdgcn_mfma_f32_16x16x32_bf16(al1, bh1, acc1, 0, 0, 0);
    acc0 = __builtin_amdgcn_mfma_f32_16x16x32_bf16(ah0, bl1, acc0, 0, 0, 0);
    acc1 = __builtin_amdgcn_mfma_f32_16x16x32_bf16(ah1, bl1, acc1, 0, 0, 0);
    UPD2(acc0, cc1, 0)
    UPD2(acc1, cc1, 4)

    bh0 = ph0; bl0 = pl0; bh1 = ph1; bl1 = pl1;
    cc0 = pc0; cc1 = pc1;
  }

  float etot = 0.f;
#pragma unroll
  for (int k = 0; k < 8; ++k) etot += accE[k];

#pragma unroll
  for (int d = 1; d < 16; d <<= 1) {
#pragma unroll
    for (int k = 0; k < 8; ++k) accP[k] += __shfl_xor(accP[k], d);
  }
#pragma unroll
  for (int k = 0; k < 8; ++k) {
    if (c == k) {
      const int g = k >> 2, r = k & 3;
      atomicAdd(&avg[cbase + g * 16 + q * 4 + r], accP[k]);
    }
  }
  __shared__ float red[256];
  red[threadIdx.x] = etot;
  __syncthreads();
  for (int st = 128; st > 0; st >>= 1) {
    if (threadIdx.x < st) red[threadIdx.x] += red[threadIdx.x + st];
    __syncthreads();
  }
  if (threadIdx.x == 0) atomicAdd(&scal[0], red[0]);
}

// --- final scalars. ---
__global__ __launch_bounds__(256) void k_final(const float* __restrict__ avg,
    const float* __restrict__ scal, float* __restrict__ out) {
  float s = 0.f;
  for (int i = threadIdx.x; i < N_E; i += 256) {
    float a = avg[i] * (1.0f / T);
    s += a * (flog2(a + 1e-5f) * LN2);
  }
  __shared__ float red[256];
  red[threadIdx.x] = s;
  __syncthreads();
  for (int st = 128; st > 0; st >>= 1) {
    if (threadIdx.x < st) red[threadIdx.x] += red[threadIdx.x + st];
    __syncthreads();
  }
  if (threadIdx.x == 0) {
    float avg_entropy = -red[0];
    float sample_entropy = -(scal[0] * LN2) * (1.0f / T);
    float vq = scal[1] * (1.0f / (T * ED));
    out[T * ED + 0] = vq;
    out[T * ED + 1] = 0.25f * vq;
    out[T * ED + 2] = 0.1f * (sample_entropy - avg_entropy);
  }
}

extern "C" void kernel_launch(void* const* d_in, const int* in_sizes, int n_in,
                              void* d_out, int out_size, void* d_ws, size_t ws_size,
                              hipStream_t stream) {
  const float* z = (const float*)d_in[0];
  const float* emb = (const float*)d_in[1];
  float* out = (float*)d_out;
  float* w = (float*)d_ws;

  float* embn = w;                          // 524288 f
  float* ses2 = embn + 524288;              // 16384
  float* zf   = ses2 + 16384;               // 262144
  float* a02  = zf + 262144;                // 8192
  short* ehl  = (short*)(a02 + 8192);       // 1048576 sh (524288 f)
  short* zhl  = ehl + 1048576;              // 524288 sh  (262144 f)
  float* pm1  = (float*)(zhl + 524288);     // NS1*T = 131072 f
  float* pm2  = pm1 + NS1 * T;              // 131072
  float* pZ   = pm2 + NS1 * T;              // 131072
  int*   pi1  = (int*)(pZ + NS1 * T);       // 131072
  int*   pi2  = pi1 + NS1 * T;              // 131072
  float* c2   = (float*)(pi2 + NS1 * T);    // 8192
  int*   idxo = (int*)(c2 + 8192);          // 8192
  float* avg  = (float*)(idxo + 8192);      // 16384
  float* scal = avg + 16384;                // 2     (~9.1 MB total)

  hipMemsetAsync(avg, 0, (16384 + 2) * sizeof(float), stream);

  k_prep_emb<<<64, 256, 0, stream>>>(emb, embn, ses2, ehl);
  k_prep_z<<<32, 256, 0, stream>>>(z, zf, a02, zhl);
  k_pass1<<<dim3(T / 128, NS1), 256, 0, stream>>>(ehl, zhl, ses2, a02,
                                                  pm1, pm2, pZ, pi1, pi2);
  k_merge<<<32, 256, 0, stream>>>(pm1, pm2, pZ, pi1, pi2, zf, embn, ses2, a02,
                                  c2, idxo, scal, out);
  k_pass2<<<dim3(N_E / 128, RS2), 256, 0, stream>>>(ehl, zhl, ses2, c2, avg, scal);
  k_final<<<1, 256, 0, stream>>>(avg, scal, out);
}

// Round 10
// 202.746 us; speedup vs baseline: 3.7459x; 1.2112x over previous
//
#include <hip/hip_runtime.h>

// VQ-VAE vector quantize + losses, MI355X.
// T=8192 rows, N_E=16384 codes, D=32.
// R10: R6 structure (best measured: NS1=16/RS2=8, (256,4), top-2 med3,
//      prefetch-1) with TILE-MAJOR LANE-ORDERED operand layout:
//      [tile][hi 64x16B][lo 64x16B]. R6-R9 evidence: both passes stall at
//      ~750cyc/wave-tile (~25% SIMD issue) regardless of occupancy/prefetch/
//      op-count -> TA/L1 throughput-bound: old [row][128B] layout made every
//      B-load a 16-line gather touching the same lines twice (hi+lo). New
//      layout: each load = contiguous 1KB (8 lines), hi/lo disjoint.

#define N_E 16384
#define ED 32
#define T 8192
#define NS1 16      // pass-1 code splits (1024 codes each)
#define RS2 8       // pass-2 row splits  (1024 rows each)

#define K2 288.53900817779268f    // 200 * log2(e)
#define NS2F -144.26950408889634f // -100 * log2(e)
#define LN2 0.6931471805599453f

typedef __attribute__((ext_vector_type(8))) short s16x8;
typedef __attribute__((ext_vector_type(4))) float f32x4;

__device__ __forceinline__ float fexp2(float x) { return __builtin_amdgcn_exp2f(x); }
__device__ __forceinline__ float flog2(float x) { return __builtin_amdgcn_logf(x); }
__device__ __forceinline__ float fmed3(float a, float b, float c) {
  return __builtin_amdgcn_fmed3f(a, b, c);
}

__device__ __forceinline__ unsigned short f2bf(float x) {
  unsigned u = __float_as_uint(x);
  unsigned r = (u + 0x7FFFu + ((u >> 16) & 1u)) >> 16;
  return (unsigned short)r;
}
__device__ __forceinline__ float bf2f(unsigned short h) {
  return __uint_as_float(((unsigned)h) << 16);
}

// exact fp32 dot of a streamed row with 8 resident float4s (by value)
__device__ __forceinline__ float dot32x(const float* __restrict__ p,
    float4 z0, float4 z1, float4 z2, float4 z3,
    float4 z4, float4 z5, float4 z6, float4 z7) {
  const float4* e = (const float4*)p;
  float a0 = 0.f, a1 = 0.f, a2 = 0.f, a3 = 0.f; float4 q;
  q = e[0]; a0 = fmaf(q.x, z0.x, a0); a0 = fmaf(q.y, z0.y, a0);
            a0 = fmaf(q.z, z0.z, a0); a0 = fmaf(q.w, z0.w, a0);
  q = e[1]; a1 = fmaf(q.x, z1.x, a1); a1 = fmaf(q.y, z1.y, a1);
            a1 = fmaf(q.z, z1.z, a1); a1 = fmaf(q.w, z1.w, a1);
  q = e[2]; a2 = fmaf(q.x, z2.x, a2); a2 = fmaf(q.y, z2.y, a2);
            a2 = fmaf(q.z, z2.z, a2); a2 = fmaf(q.w, z2.w, a2);
  q = e[3]; a3 = fmaf(q.x, z3.x, a3); a3 = fmaf(q.y, z3.y, a3);
            a3 = fmaf(q.z, z3.z, a3); a3 = fmaf(q.w, z3.w, a3);
  q = e[4]; a0 = fmaf(q.x, z4.x, a0); a0 = fmaf(q.y, z4.y, a0);
            a0 = fmaf(q.z, z4.z, a0); a0 = fmaf(q.w, z4.w, a0);
  q = e[5]; a1 = fmaf(q.x, z5.x, a1); a1 = fmaf(q.y, z5.y, a1);
            a1 = fmaf(q.z, z5.z, a1); a1 = fmaf(q.w, z5.w, a1);
  q = e[6]; a2 = fmaf(q.x, z6.x, a2); a2 = fmaf(q.y, z6.y, a2);
            a2 = fmaf(q.z, z6.z, a2); a2 = fmaf(q.w, z6.w, a2);
  q = e[7]; a3 = fmaf(q.x, z7.x, a3); a3 = fmaf(q.y, z7.y, a3);
            a3 = fmaf(q.z, z7.z, a3); a3 = fmaf(q.w, z7.w, a3);
  return (a0 + a1) + (a2 + a3);
}

// split 8 floats (scaled by sc) of row `row`, group g into hi/lo bf16 frags,
// stored TILE-MAJOR: dst[tile*128 + g*16 + c] (hi), +64 (lo); s16x8 units.
__device__ __forceinline__ void split_store_t(short* __restrict__ base,
    int row, int g, float4 va, float4 vb, float sc) {
  float f[8] = { va.x * sc, va.y * sc, va.z * sc, va.w * sc,
                 vb.x * sc, vb.y * sc, vb.z * sc, vb.w * sc };
  s16x8 H, L;
#pragma unroll
  for (int e = 0; e < 8; ++e) {
    unsigned short h = f2bf(f[e]);
    H[e] = (short)h;
    L[e] = (short)f2bf(f[e] - bf2f(h));
  }
  s16x8* p = (s16x8*)base;
  const int tile = row >> 4, c = row & 15;
  p[tile * 128 + g * 16 + c] = H;
  p[tile * 128 + 64 + g * 16 + c] = L;
}

// --- prep: normalize embedding rows; fp32 + tile-major bf16 hi/lo + ses2 ---
__global__ __launch_bounds__(256) void k_prep_emb(const float* __restrict__ emb,
    float* __restrict__ embn, float* __restrict__ ses2, short* __restrict__ ehl) {
  int n = blockIdx.x * 256 + threadIdx.x;
  const float4* r4 = (const float4*)(emb + (size_t)n * ED);
  float4 v[8]; float s = 0.f;
#pragma unroll
  for (int j = 0; j < 8; ++j) {
    v[j] = r4[j];
    s = fmaf(v[j].x, v[j].x, s); s = fmaf(v[j].y, v[j].y, s);
    s = fmaf(v[j].z, v[j].z, s); s = fmaf(v[j].w, v[j].w, s);
  }
  float inv = 1.0f / fmaxf(sqrtf(s), 1e-12f);
  float s2 = 0.f;
  float4* o4 = (float4*)(embn + (size_t)n * ED);
#pragma unroll
  for (int j = 0; j < 8; ++j) {
    float4 w; w.x = v[j].x * inv; w.y = v[j].y * inv;
    w.z = v[j].z * inv; w.w = v[j].w * inv;
    o4[j] = w; v[j] = w;
    s2 = fmaf(w.x, w.x, s2); s2 = fmaf(w.y, w.y, s2);
    s2 = fmaf(w.z, w.z, s2); s2 = fmaf(w.w, w.w, s2);
  }
  ses2[n] = NS2F * s2;
#pragma unroll
  for (int g = 0; g < 4; ++g)
    split_store_t(ehl, n, g, v[2 * g], v[2 * g + 1], 1.0f);
}

// --- prep: transpose+normalize z; fp32 zf + K2-prescaled tile-major hi/lo ---
__global__ __launch_bounds__(256) void k_prep_z(const float* __restrict__ z,
    float* __restrict__ zf, float* __restrict__ a02, short* __restrict__ zhl) {
  int t = blockIdx.x * 256 + threadIdx.x;
  int b = t >> 8, hw = t & 255;
  const float* base = z + (size_t)b * (ED * 256) + hw;
  float4 v[8]; float s = 0.f;
#pragma unroll
  for (int j = 0; j < 8; ++j) {
    float4 w;
    w.x = base[(4 * j + 0) * 256]; w.y = base[(4 * j + 1) * 256];
    w.z = base[(4 * j + 2) * 256]; w.w = base[(4 * j + 3) * 256];
    v[j] = w;
    s = fmaf(w.x, w.x, s); s = fmaf(w.y, w.y, s);
    s = fmaf(w.z, w.z, s); s = fmaf(w.w, w.w, s);
  }
  float inv = 1.0f / fmaxf(sqrtf(s), 1e-12f);
  float s2 = 0.f;
  float4* o4 = (float4*)(zf + (size_t)t * ED);
#pragma unroll
  for (int j = 0; j < 8; ++j) {
    float4 w; w.x = v[j].x * inv; w.y = v[j].y * inv;
    w.z = v[j].z * inv; w.w = v[j].w * inv;
    o4[j] = w; v[j] = w;
    s2 = fmaf(w.x, w.x, s2); s2 = fmaf(w.y, w.y, s2);
    s2 = fmaf(w.z, w.z, s2); s2 = fmaf(w.w, w.w, s2);
  }
  a02[t] = NS2F * s2;
#pragma unroll
  for (int g = 0; g < 4; ++g)
    split_store_t(zhl, t, g, v[2 * g], v[2 * g + 1], K2);
}

// --- pass 1: wave owns 32 rows, sweeps a 1024-code split in 16-code tiles.
//     acc C-init = a02+80; fb = acc + ses2[code]. med3 top-2 + biased Z.
//     B loads: contiguous 1KB per frag (tile-major layout). ---
__global__ __launch_bounds__(256, 4) void k_pass1(
    const short* __restrict__ ehl, const short* __restrict__ zhl,
    const float* __restrict__ ses2, const float* __restrict__ a02,
    float* __restrict__ pm1, float* __restrict__ pm2, float* __restrict__ pZ,
    int* __restrict__ pi1, int* __restrict__ pi2) {
  const int lane = threadIdx.x & 63, wv = threadIdx.x >> 6;
  const int q = lane >> 4, c = lane & 15;
  const int rowbase = blockIdx.x * 128 + wv * 32;
  const int nb0 = blockIdx.y * (N_E / NS1);
  const int NT = (N_E / NS1) / 16;  // 64

  const s16x8* zg = (const s16x8*)zhl;
  const int atile = rowbase >> 4;
  s16x8 ah0 = zg[atile * 128 + lane],         al0 = zg[atile * 128 + 64 + lane];
  s16x8 ah1 = zg[(atile + 1) * 128 + lane],   al1 = zg[(atile + 1) * 128 + 64 + lane];

  f32x4 bias0, bias1;
#pragma unroll
  for (int r = 0; r < 4; ++r) {
    bias0[r] = a02[rowbase + q * 4 + r] + 80.0f;
    bias1[r] = a02[rowbase + 16 + q * 4 + r] + 80.0f;
  }

  float m1[8], m2[8], Zs[8]; int i1[8], i2[8];
#pragma unroll
  for (int k = 0; k < 8; ++k) {
    m1[k] = -1e30f; m2[k] = -1e30f; Zs[k] = 0.f;
    i1[k] = nb0 + c; i2[k] = nb0 + c;
  }

  const s16x8* eg = (const s16x8*)ehl;
  const int btile0 = nb0 >> 4;
  s16x8 bh = eg[btile0 * 128 + lane], bl = eg[btile0 * 128 + 64 + lane];
  float sesc = ses2[nb0 + c];

  for (int tile = 0; tile < NT; ++tile) {
    const int nx = (tile + 1 < NT) ? tile + 1 : tile;     // uniform
    const int nidx = (btile0 + nx) * 128 + lane;
    s16x8 nh = eg[nidx], nl = eg[nidx + 64];              // prefetch (2x1KB)
    float nses = ses2[nb0 + nx * 16 + c];

    f32x4 acc0 = __builtin_amdgcn_mfma_f32_16x16x32_bf16(ah0, bh, bias0, 0, 0, 0);
    f32x4 acc1 = __builtin_amdgcn_mfma_f32_16x16x32_bf16(ah1, bh, bias1, 0, 0, 0);
    acc0 = __builtin_amdgcn_mfma_f32_16x16x32_bf16(al0, bh, acc0, 0, 0, 0);
    acc1 = __builtin_amdgcn_mfma_f32_16x16x32_bf16(al1, bh, acc1, 0, 0, 0);
    acc0 = __builtin_amdgcn_mfma_f32_16x16x32_bf16(ah0, bl, acc0, 0, 0, 0);
    acc1 = __builtin_amdgcn_mfma_f32_16x16x32_bf16(ah1, bl, acc1, 0, 0, 0);

    const int vn = nb0 + tile * 16 + c;
#pragma unroll
    for (int g = 0; g < 2; ++g) {
#pragma unroll
      for (int r = 0; r < 4; ++r) {
        const int k = g * 4 + r;
        float fb = ((g == 0) ? acc0[r] : acc1[r]) + sesc;
        bool g1 = fb > m1[k];
        bool g2 = fb > m2[k];
        i2[k] = g1 ? i1[k] : (g2 ? vn : i2[k]);
        m2[k] = fmed3(fb, m1[k], m2[k]);   // 2nd-max of {m1,m2,fb}
        i1[k] = g1 ? vn : i1[k];
        m1[k] = fmaxf(m1[k], fb);
        Zs[k] += fexp2(fb);
      }
    }
    bh = nh; bl = nl; sesc = nses;
  }

  // reduce across the 16 cols within each quad
#pragma unroll
  for (int d = 1; d < 16; d <<= 1) {
#pragma unroll
    for (int k = 0; k < 8; ++k) {
      float om1 = __shfl_xor(m1[k], d);
      float om2 = __shfl_xor(m2[k], d);
      float oZ = __shfl_xor(Zs[k], d);
      int oi1 = __shfl_xor(i1[k], d);
      int oi2 = __shfl_xor(i2[k], d);
      bool c1 = om1 > m1[k];
      float lm = c1 ? m1[k] : om1;
      int li = c1 ? i1[k] : oi1;
      float nm1 = c1 ? om1 : m1[k];
      int ni1 = c1 ? oi1 : i1[k];
      bool cb = om2 > m2[k];
      float mm2 = cb ? om2 : m2[k];
      int mi2 = cb ? oi2 : i2[k];
      bool c3 = mm2 > lm;
      m1[k] = nm1; i1[k] = ni1;
      m2[k] = c3 ? mm2 : lm;
      i2[k] = c3 ? mi2 : li;
      Zs[k] += oZ;
    }
  }

#pragma unroll
  for (int k = 0; k < 8; ++k) {
    if (c == k) {
      const int g = k >> 2, r = k & 3;
      const int t = rowbase + g * 16 + q * 4 + r;
      const int p = blockIdx.y * T + t;
      pm1[p] = m1[k]; pm2[p] = m2[k]; pZ[p] = Zs[k];
      pi1[p] = i1[k]; pi2[p] = i2[k];
    }
  }
}

// --- merge: combine split partials; exact fp32 re-compare of candidates;
//     lse2, c2 = a02 - lse2, vq sum-of-squares, straight-through output. ---
__global__ __launch_bounds__(256) void k_merge(
    const float* __restrict__ pm1, const float* __restrict__ pm2,
    const float* __restrict__ pZ, const int* __restrict__ pi1,
    const int* __restrict__ pi2, const float* __restrict__ zf,
    const float* __restrict__ embn, const float* __restrict__ ses2,
    const float* __restrict__ a02, float* __restrict__ c2,
    int* __restrict__ idxo, float* __restrict__ scal, float* __restrict__ out) {
  const int t = blockIdx.x * 256 + threadIdx.x;
  float m1 = -1e30f, m2 = -1e30f, Z = 0.f;
  int i1 = 0, i2 = 0;
  for (int s = 0; s < NS1; ++s) {
    const int p = s * T + t;
    float sm1 = pm1[p], sm2 = pm2[p];
    int si1 = pi1[p], si2 = pi2[p];
    Z += pZ[p];
    bool c1 = sm1 > m1;
    float lm = c1 ? m1 : sm1;
    int li = c1 ? i1 : si1;
    float nm1 = c1 ? sm1 : m1;
    int ni1 = c1 ? si1 : i1;
    bool cb = sm2 > m2;
    float mm2 = cb ? sm2 : m2;
    int mi2 = cb ? si2 : i2;
    bool c3 = mm2 > lm;
    m1 = nm1; i1 = ni1;
    m2 = c3 ? mm2 : lm;
    i2 = c3 ? mi2 : li;
  }
  const float a02t = a02[t];
  const float lse2 = flog2(Z) - 80.0f;
  c2[t] = a02t - lse2;

  const float4* zr4 = (const float4*)(zf + (size_t)t * ED);
  float4 z0 = zr4[0], z1 = zr4[1], z2 = zr4[2], z3 = zr4[3];
  float4 z4 = zr4[4], z5 = zr4[5], z6 = zr4[6], z7 = zr4[7];
  float d1 = dot32x(embn + (size_t)i1 * ED, z0, z1, z2, z3, z4, z5, z6, z7);
  float d2 = dot32x(embn + (size_t)i2 * ED, z0, z1, z2, z3, z4, z5, z6, z7);
  float fb1 = fmaf(K2, d1, a02t + ses2[i1]);
  float fb2 = fmaf(K2, d2, a02t + ses2[i2]);
  int bi = (fb2 > fb1 || (fb2 == fb1 && i2 < i1)) ? i2 : i1;
  idxo[t] = bi;

  // vq sum-of-squares + straight-through output (out = zb + (z_q - zb))
  const int b = t >> 8, hw = t & 255;
  float* ob = out + (size_t)b * (ED * 256) + hw;
  float ss = 0.f;
  const float4* e4 = (const float4*)(embn + (size_t)bi * ED);
#pragma unroll
  for (int j = 0; j < 8; ++j) {
    float4 qv = e4[j];
    float4 zv = (j == 0) ? z0 : (j == 1) ? z1 : (j == 2) ? z2 : (j == 3) ? z3
              : (j == 4) ? z4 : (j == 5) ? z5 : (j == 6) ? z6 : z7;
    float df;
    df = qv.x - zv.x; ss = fmaf(df, df, ss); ob[(4 * j + 0) * 256] = zv.x + (qv.x - zv.x);
    df = qv.y - zv.y; ss = fmaf(df, df, ss); ob[(4 * j + 1) * 256] = zv.y + (qv.y - zv.y);
    df = qv.z - zv.z; ss = fmaf(df, df, ss); ob[(4 * j + 2) * 256] = zv.z + (qv.z - zv.z);
    df = qv.w - zv.w; ss = fmaf(df, df, ss); ob[(4 * j + 3) * 256] = zv.w + (qv.w - zv.w);
  }
  __shared__ float red[256];
  red[threadIdx.x] = ss;
  __syncthreads();
  for (int st = 128; st > 0; st >>= 1) {
    if (threadIdx.x < st) red[threadIdx.x] += red[threadIdx.x + st];
    __syncthreads();
  }
  if (threadIdx.x == 0) atomicAdd(&scal[1], red[0]);
}

// --- pass 2: wave owns 32 codes, sweeps a 1024-row split in 16-row tiles.
//     acc C-init = ses2[code]; dl = acc + c2[t] = fb - lse2 (<=0). ---
__global__ __launch_bounds__(256, 4) void k_pass2(
    const short* __restrict__ ehl, const short* __restrict__ zhl,
    const float* __restrict__ ses2, const float* __restrict__ c2,
    float* __restrict__ avg, float* __restrict__ scal) {
  const int lane = threadIdx.x & 63, wv = threadIdx.x >> 6;
  const int q = lane >> 4, c = lane & 15;
  const int cbase = blockIdx.x * 128 + wv * 32;
  const int tb0 = blockIdx.y * (T / RS2);
  const int NT = (T / RS2) / 16;  // 64

  const s16x8* eg = (const s16x8*)ehl;
  const int atile = cbase >> 4;
  s16x8 ah0 = eg[atile * 128 + lane],       al0 = eg[atile * 128 + 64 + lane];
  s16x8 ah1 = eg[(atile + 1) * 128 + lane], al1 = eg[(atile + 1) * 128 + 64 + lane];

  f32x4 sg0, sg1;
#pragma unroll
  for (int r = 0; r < 4; ++r) {
    sg0[r] = ses2[cbase + q * 4 + r];
    sg1[r] = ses2[cbase + 16 + q * 4 + r];
  }

  float accP[8], accE[8];
#pragma unroll
  for (int k = 0; k < 8; ++k) { accP[k] = 0.f; accE[k] = 0.f; }

  const s16x8* zg = (const s16x8*)zhl;
  const int btile0 = tb0 >> 4;
  s16x8 bh = zg[btile0 * 128 + lane], bl = zg[btile0 * 128 + 64 + lane];
  float cc = c2[tb0 + c];

  for (int tile = 0; tile < NT; ++tile) {
    const int nx = (tile + 1 < NT) ? tile + 1 : tile;
    const int nidx = (btile0 + nx) * 128 + lane;
    s16x8 nh = zg[nidx], nl = zg[nidx + 64];              // prefetch (2x1KB)
    float ncc = c2[tb0 + nx * 16 + c];

    f32x4 acc0 = __builtin_amdgcn_mfma_f32_16x16x32_bf16(ah0, bh, sg0, 0, 0, 0);
    f32x4 acc1 = __builtin_amdgcn_mfma_f32_16x16x32_bf16(ah1, bh, sg1, 0, 0, 0);
    acc0 = __builtin_amdgcn_mfma_f32_16x16x32_bf16(al0, bh, acc0, 0, 0, 0);
    acc1 = __builtin_amdgcn_mfma_f32_16x16x32_bf16(al1, bh, acc1, 0, 0, 0);
    acc0 = __builtin_amdgcn_mfma_f32_16x16x32_bf16(ah0, bl, acc0, 0, 0, 0);
    acc1 = __builtin_amdgcn_mfma_f32_16x16x32_bf16(ah1, bl, acc1, 0, 0, 0);

#pragma unroll
    for (int g = 0; g < 2; ++g) {
#pragma unroll
      for (int r = 0; r < 4; ++r) {
        const int k = g * 4 + r;
        float dl = ((g == 0) ? acc0[r] : acc1[r]) + cc;  // fb - lse2 (<=0)
        float p = fexp2(dl);                              // underflow -> 0
        accP[k] += p;
        accE[k] = fmaf(p, dl, accE[k]);
      }
    }
    bh = nh; bl = nl; cc = ncc;
  }

  float etot = 0.f;
#pragma unroll
  for (int k = 0; k < 8; ++k) etot += accE[k];

#pragma unroll
  for (int d = 1; d < 16; d <<= 1) {
#pragma unroll
    for (int k = 0; k < 8; ++k) accP[k] += __shfl_xor(accP[k], d);
  }
#pragma unroll
  for (int k = 0; k < 8; ++k) {
    if (c == k) {
      const int g = k >> 2, r = k & 3;
      atomicAdd(&avg[cbase + g * 16 + q * 4 + r], accP[k]);
    }
  }
  __shared__ float red[256];
  red[threadIdx.x] = etot;
  __syncthreads();
  for (int st = 128; st > 0; st >>= 1) {
    if (threadIdx.x < st) red[threadIdx.x] += red[threadIdx.x + st];
    __syncthreads();
  }
  if (threadIdx.x == 0) atomicAdd(&scal[0], red[0]);
}

// --- final scalars. ---
__global__ __launch_bounds__(256) void k_final(const float* __restrict__ avg,
    const float* __restrict__ scal, float* __restrict__ out) {
  float s = 0.f;
  for (int i = threadIdx.x; i < N_E; i += 256) {
    float a = avg[i] * (1.0f / T);
    s += a * (flog2(a + 1e-5f) * LN2);
  }
  __shared__ float red[256];
  red[threadIdx.x] = s;
  __syncthreads();
  for (int st = 128; st > 0; st >>= 1) {
    if (threadIdx.x < st) red[threadIdx.x] += red[threadIdx.x + st];
    __syncthreads();
  }
  if (threadIdx.x == 0) {
    float avg_entropy = -red[0];
    float sample_entropy = -(scal[0] * LN2) * (1.0f / T);
    float vq = scal[1] * (1.0f / (T * ED));
    out[T * ED + 0] = vq;
    out[T * ED + 1] = 0.25f * vq;
    out[T * ED + 2] = 0.1f * (sample_entropy - avg_entropy);
  }
}

extern "C" void kernel_launch(void* const* d_in, const int* in_sizes, int n_in,
                              void* d_out, int out_size, void* d_ws, size_t ws_size,
                              hipStream_t stream) {
  const float* z = (const float*)d_in[0];
  const float* emb = (const float*)d_in[1];
  float* out = (float*)d_out;
  float* w = (float*)d_ws;

  float* embn = w;                          // 524288 f
  float* ses2 = embn + 524288;              // 16384
  float* zf   = ses2 + 16384;               // 262144
  float* a02  = zf + 262144;                // 8192
  short* ehl  = (short*)(a02 + 8192);       // 1048576 sh (524288 f)
  short* zhl  = ehl + 1048576;              // 524288 sh  (262144 f)
  float* pm1  = (float*)(zhl + 524288);     // NS1*T = 131072 f
  float* pm2  = pm1 + NS1 * T;              // 131072
  float* pZ   = pm2 + NS1 * T;              // 131072
  int*   pi1  = (int*)(pZ + NS1 * T);       // 131072
  int*   pi2  = pi1 + NS1 * T;              // 131072
  float* c2   = (float*)(pi2 + NS1 * T);    // 8192
  int*   idxo = (int*)(c2 + 8192);          // 8192
  float* avg  = (float*)(idxo + 8192);      // 16384
  float* scal = avg + 16384;                // 2     (~9.1 MB total)

  hipMemsetAsync(avg, 0, (16384 + 2) * sizeof(float), stream);

  k_prep_emb<<<64, 256, 0, stream>>>(emb, embn, ses2, ehl);
  k_prep_z<<<32, 256, 0, stream>>>(z, zf, a02, zhl);
  k_pass1<<<dim3(T / 128, NS1), 256, 0, stream>>>(ehl, zhl, ses2, a02,
                                                  pm1, pm2, pZ, pi1, pi2);
  k_merge<<<32, 256, 0, stream>>>(pm1, pm2, pZ, pi1, pi2, zf, embn, ses2, a02,
                                  c2, idxo, scal, out);
  k_pass2<<<dim3(N_E / 128, RS2), 256, 0, stream>>>(ehl, zhl, ses2, c2, avg, scal);
  k_final<<<1, 256, 0, stream>>>(avg, scal, out);
}

// Round 11
// 181.295 us; speedup vs baseline: 4.1892x; 1.1183x over previous
//
#include <hip/hip_runtime.h>

// VQ-VAE vector quantize + losses, MI355X.
// T=8192 rows, N_E=16384 codes, D=32.
// R11: R10 (tile-major operands; pass2 fixed) + pass1 epilogue diet:
//      top-2 via mantissa-packed keys (tile idx in low 6 bits; med3+max only,
//      no cmps/cndmasks; indices decoded post-loop) -- pass1 is VALU-issue-
//      bound (R10: 750cyc/tile == 4 waves x issue est.). Also preps fused
//      into one kernel (launch-gap ~40us total across 7 kernels).

#define N_E 16384
#define ED 32
#define T 8192
#define NS1 16      // pass-1 code splits (1024 codes each)
#define RS2 8       // pass-2 row splits  (1024 rows each)

#define K2 288.53900817779268f    // 200 * log2(e)
#define NS2F -144.26950408889634f // -100 * log2(e)
#define LN2 0.6931471805599453f

typedef __attribute__((ext_vector_type(8))) short s16x8;
typedef __attribute__((ext_vector_type(4))) float f32x4;

__device__ __forceinline__ float fexp2(float x) { return __builtin_amdgcn_exp2f(x); }
__device__ __forceinline__ float flog2(float x) { return __builtin_amdgcn_logf(x); }
__device__ __forceinline__ float fmed3(float a, float b, float c) {
  return __builtin_amdgcn_fmed3f(a, b, c);
}

__device__ __forceinline__ unsigned short f2bf(float x) {
  unsigned u = __float_as_uint(x);
  unsigned r = (u + 0x7FFFu + ((u >> 16) & 1u)) >> 16;
  return (unsigned short)r;
}
__device__ __forceinline__ float bf2f(unsigned short h) {
  return __uint_as_float(((unsigned)h) << 16);
}

// exact fp32 dot of a streamed row with 8 resident float4s (by value)
__device__ __forceinline__ float dot32x(const float* __restrict__ p,
    float4 z0, float4 z1, float4 z2, float4 z3,
    float4 z4, float4 z5, float4 z6, float4 z7) {
  const float4* e = (const float4*)p;
  float a0 = 0.f, a1 = 0.f, a2 = 0.f, a3 = 0.f; float4 q;
  q = e[0]; a0 = fmaf(q.x, z0.x, a0); a0 = fmaf(q.y, z0.y, a0);
            a0 = fmaf(q.z, z0.z, a0); a0 = fmaf(q.w, z0.w, a0);
  q = e[1]; a1 = fmaf(q.x, z1.x, a1); a1 = fmaf(q.y, z1.y, a1);
            a1 = fmaf(q.z, z1.z, a1); a1 = fmaf(q.w, z1.w, a1);
  q = e[2]; a2 = fmaf(q.x, z2.x, a2); a2 = fmaf(q.y, z2.y, a2);
            a2 = fmaf(q.z, z2.z, a2); a2 = fmaf(q.w, z2.w, a2);
  q = e[3]; a3 = fmaf(q.x, z3.x, a3); a3 = fmaf(q.y, z3.y, a3);
            a3 = fmaf(q.z, z3.z, a3); a3 = fmaf(q.w, z3.w, a3);
  q = e[4]; a0 = fmaf(q.x, z4.x, a0); a0 = fmaf(q.y, z4.y, a0);
            a0 = fmaf(q.z, z4.z, a0); a0 = fmaf(q.w, z4.w, a0);
  q = e[5]; a1 = fmaf(q.x, z5.x, a1); a1 = fmaf(q.y, z5.y, a1);
            a1 = fmaf(q.z, z5.z, a1); a1 = fmaf(q.w, z5.w, a1);
  q = e[6]; a2 = fmaf(q.x, z6.x, a2); a2 = fmaf(q.y, z6.y, a2);
            a2 = fmaf(q.z, z6.z, a2); a2 = fmaf(q.w, z6.w, a2);
  q = e[7]; a3 = fmaf(q.x, z7.x, a3); a3 = fmaf(q.y, z7.y, a3);
            a3 = fmaf(q.z, z7.z, a3); a3 = fmaf(q.w, z7.w, a3);
  return (a0 + a1) + (a2 + a3);
}

// split 8 floats (scaled by sc) of row `row`, group g into hi/lo bf16 frags,
// stored TILE-MAJOR: dst[tile*128 + g*16 + c] (hi), +64 (lo); s16x8 units.
__device__ __forceinline__ void split_store_t(short* __restrict__ base,
    int row, int g, float4 va, float4 vb, float sc) {
  float f[8] = { va.x * sc, va.y * sc, va.z * sc, va.w * sc,
                 vb.x * sc, vb.y * sc, vb.z * sc, vb.w * sc };
  s16x8 H, L;
#pragma unroll
  for (int e = 0; e < 8; ++e) {
    unsigned short h = f2bf(f[e]);
    H[e] = (short)h;
    L[e] = (short)f2bf(f[e] - bf2f(h));
  }
  s16x8* p = (s16x8*)base;
  const int tile = row >> 4, c = row & 15;
  p[tile * 128 + g * 16 + c] = H;
  p[tile * 128 + 64 + g * 16 + c] = L;
}

// --- fused prep: blocks 0..63 normalize embedding rows; 64..95 transpose+
//     normalize z. fp32 copies + tile-major bf16 hi/lo + fb-unit norms. ---
__global__ __launch_bounds__(256) void k_prep(const float* __restrict__ emb,
    const float* __restrict__ z, float* __restrict__ embn,
    float* __restrict__ ses2, float* __restrict__ zf, float* __restrict__ a02,
    short* __restrict__ ehl, short* __restrict__ zhl) {
  if (blockIdx.x < 64) {
    int n = blockIdx.x * 256 + threadIdx.x;
    const float4* r4 = (const float4*)(emb + (size_t)n * ED);
    float4 v[8]; float s = 0.f;
#pragma unroll
    for (int j = 0; j < 8; ++j) {
      v[j] = r4[j];
      s = fmaf(v[j].x, v[j].x, s); s = fmaf(v[j].y, v[j].y, s);
      s = fmaf(v[j].z, v[j].z, s); s = fmaf(v[j].w, v[j].w, s);
    }
    float inv = 1.0f / fmaxf(sqrtf(s), 1e-12f);
    float s2 = 0.f;
    float4* o4 = (float4*)(embn + (size_t)n * ED);
#pragma unroll
    for (int j = 0; j < 8; ++j) {
      float4 w; w.x = v[j].x * inv; w.y = v[j].y * inv;
      w.z = v[j].z * inv; w.w = v[j].w * inv;
      o4[j] = w; v[j] = w;
      s2 = fmaf(w.x, w.x, s2); s2 = fmaf(w.y, w.y, s2);
      s2 = fmaf(w.z, w.z, s2); s2 = fmaf(w.w, w.w, s2);
    }
    ses2[n] = NS2F * s2;
#pragma unroll
    for (int g = 0; g < 4; ++g)
      split_store_t(ehl, n, g, v[2 * g], v[2 * g + 1], 1.0f);
  } else {
    int t = (blockIdx.x - 64) * 256 + threadIdx.x;
    int b = t >> 8, hw = t & 255;
    const float* base = z + (size_t)b * (ED * 256) + hw;
    float4 v[8]; float s = 0.f;
#pragma unroll
    for (int j = 0; j < 8; ++j) {
      float4 w;
      w.x = base[(4 * j + 0) * 256]; w.y = base[(4 * j + 1) * 256];
      w.z = base[(4 * j + 2) * 256]; w.w = base[(4 * j + 3) * 256];
      v[j] = w;
      s = fmaf(w.x, w.x, s); s = fmaf(w.y, w.y, s);
      s = fmaf(w.z, w.z, s); s = fmaf(w.w, w.w, s);
    }
    float inv = 1.0f / fmaxf(sqrtf(s), 1e-12f);
    float s2 = 0.f;
    float4* o4 = (float4*)(zf + (size_t)t * ED);
#pragma unroll
    for (int j = 0; j < 8; ++j) {
      float4 w; w.x = v[j].x * inv; w.y = v[j].y * inv;
      w.z = v[j].z * inv; w.w = v[j].w * inv;
      o4[j] = w; v[j] = w;
      s2 = fmaf(w.x, w.x, s2); s2 = fmaf(w.y, w.y, s2);
      s2 = fmaf(w.z, w.z, s2); s2 = fmaf(w.w, w.w, s2);
    }
    a02[t] = NS2F * s2;
#pragma unroll
    for (int g = 0; g < 4; ++g)
      split_store_t(zhl, t, g, v[2 * g], v[2 * g + 1], K2);
  }
}

// --- pass 1: wave owns 32 rows, sweeps a 1024-code split in 16-code tiles.
//     acc C-init = a02+80; fb = acc + ses2[code]. Top-2 via mantissa-packed
//     keys: low 6 fb-mantissa bits replaced by tile idx; med3+max only.
//     Keys decoded to indices post-loop (lane's own c known). Quantization
//     (<=2^-11 at the decision region) is inside the exact-refine budget. ---
__global__ __launch_bounds__(256, 4) void k_pass1(
    const short* __restrict__ ehl, const short* __restrict__ zhl,
    const float* __restrict__ ses2, const float* __restrict__ a02,
    float* __restrict__ pm1, float* __restrict__ pm2, float* __restrict__ pZ,
    int* __restrict__ pi1, int* __restrict__ pi2) {
  const int lane = threadIdx.x & 63, wv = threadIdx.x >> 6;
  const int q = lane >> 4, c = lane & 15;
  const int rowbase = blockIdx.x * 128 + wv * 32;
  const int nb0 = blockIdx.y * (N_E / NS1);
  const int NT = (N_E / NS1) / 16;  // 64

  const s16x8* zg = (const s16x8*)zhl;
  const int atile = rowbase >> 4;
  s16x8 ah0 = zg[atile * 128 + lane],         al0 = zg[atile * 128 + 64 + lane];
  s16x8 ah1 = zg[(atile + 1) * 128 + lane],   al1 = zg[(atile + 1) * 128 + 64 + lane];

  f32x4 bias0, bias1;
#pragma unroll
  for (int r = 0; r < 4; ++r) {
    bias0[r] = a02[rowbase + q * 4 + r] + 80.0f;
    bias1[r] = a02[rowbase + 16 + q * 4 + r] + 80.0f;
  }

  float m1[8], m2[8], Zs[8];
#pragma unroll
  for (int k = 0; k < 8; ++k) { m1[k] = -1e30f; m2[k] = -1e30f; Zs[k] = 0.f; }

  const s16x8* eg = (const s16x8*)ehl;
  const int btile0 = nb0 >> 4;
  s16x8 bh = eg[btile0 * 128 + lane], bl = eg[btile0 * 128 + 64 + lane];
  float sesc = ses2[nb0 + c];

  for (int tile = 0; tile < NT; ++tile) {
    const int nx = (tile + 1 < NT) ? tile + 1 : tile;     // uniform
    const int nidx = (btile0 + nx) * 128 + lane;
    s16x8 nh = eg[nidx], nl = eg[nidx + 64];              // prefetch (2x1KB)
    float nses = ses2[nb0 + nx * 16 + c];

    f32x4 acc0 = __builtin_amdgcn_mfma_f32_16x16x32_bf16(ah0, bh, bias0, 0, 0, 0);
    f32x4 acc1 = __builtin_amdgcn_mfma_f32_16x16x32_bf16(ah1, bh, bias1, 0, 0, 0);
    acc0 = __builtin_amdgcn_mfma_f32_16x16x32_bf16(al0, bh, acc0, 0, 0, 0);
    acc1 = __builtin_amdgcn_mfma_f32_16x16x32_bf16(al1, bh, acc1, 0, 0, 0);
    acc0 = __builtin_amdgcn_mfma_f32_16x16x32_bf16(ah0, bl, acc0, 0, 0, 0);
    acc1 = __builtin_amdgcn_mfma_f32_16x16x32_bf16(ah1, bl, acc1, 0, 0, 0);

    const unsigned tu = (unsigned)tile;                   // uniform 6-bit idx
#pragma unroll
    for (int g = 0; g < 2; ++g) {
#pragma unroll
      for (int r = 0; r < 4; ++r) {
        const int k = g * 4 + r;
        float fb = ((g == 0) ? acc0[r] : acc1[r]) + sesc;
        float key = __uint_as_float((__float_as_uint(fb) & 0xFFFFFFC0u) | tu);
        m2[k] = fmed3(key, m1[k], m2[k]);   // 2nd-max of {key,m1,m2}
        m1[k] = fmaxf(m1[k], key);
        Zs[k] += fexp2(fb);
      }
    }
    bh = nh; bl = nl; sesc = nses;
  }

  // decode indices from this lane's own keys (c local), then reduce
  int i1[8], i2[8];
#pragma unroll
  for (int k = 0; k < 8; ++k) {
    i1[k] = nb0 + (int)((__float_as_uint(m1[k]) & 63u) << 4) + c;
    i2[k] = nb0 + (int)((__float_as_uint(m2[k]) & 63u) << 4) + c;
  }

  // reduce across the 16 cols within each quad
#pragma unroll
  for (int d = 1; d < 16; d <<= 1) {
#pragma unroll
    for (int k = 0; k < 8; ++k) {
      float om1 = __shfl_xor(m1[k], d);
      float om2 = __shfl_xor(m2[k], d);
      float oZ = __shfl_xor(Zs[k], d);
      int oi1 = __shfl_xor(i1[k], d);
      int oi2 = __shfl_xor(i2[k], d);
      bool c1 = om1 > m1[k];
      float lm = c1 ? m1[k] : om1;
      int li = c1 ? i1[k] : oi1;
      float nm1 = c1 ? om1 : m1[k];
      int ni1 = c1 ? oi1 : i1[k];
      bool cb = om2 > m2[k];
      float mm2 = cb ? om2 : m2[k];
      int mi2 = cb ? oi2 : i2[k];
      bool c3 = mm2 > lm;
      m1[k] = nm1; i1[k] = ni1;
      m2[k] = c3 ? mm2 : lm;
      i2[k] = c3 ? mi2 : li;
      Zs[k] += oZ;
    }
  }

#pragma unroll
  for (int k = 0; k < 8; ++k) {
    if (c == k) {
      const int g = k >> 2, r = k & 3;
      const int t = rowbase + g * 16 + q * 4 + r;
      const int p = blockIdx.y * T + t;
      pm1[p] = m1[k]; pm2[p] = m2[k]; pZ[p] = Zs[k];
      pi1[p] = i1[k]; pi2[p] = i2[k];
    }
  }
}

// --- merge: combine split partials; exact fp32 re-compare of candidates;
//     lse2, c2 = a02 - lse2, vq sum-of-squares, straight-through output. ---
__global__ __launch_bounds__(256) void k_merge(
    const float* __restrict__ pm1, const float* __restrict__ pm2,
    const float* __restrict__ pZ, const int* __restrict__ pi1,
    const int* __restrict__ pi2, const float* __restrict__ zf,
    const float* __restrict__ embn, const float* __restrict__ ses2,
    const float* __restrict__ a02, float* __restrict__ c2,
    int* __restrict__ idxo, float* __restrict__ scal, float* __restrict__ out) {
  const int t = blockIdx.x * 256 + threadIdx.x;
  float m1 = -1e30f, m2 = -1e30f, Z = 0.f;
  int i1 = 0, i2 = 0;
  for (int s = 0; s < NS1; ++s) {
    const int p = s * T + t;
    float sm1 = pm1[p], sm2 = pm2[p];
    int si1 = pi1[p], si2 = pi2[p];
    Z += pZ[p];
    bool c1 = sm1 > m1;
    float lm = c1 ? m1 : sm1;
    int li = c1 ? i1 : si1;
    float nm1 = c1 ? sm1 : m1;
    int ni1 = c1 ? si1 : i1;
    bool cb = sm2 > m2;
    float mm2 = cb ? sm2 : m2;
    int mi2 = cb ? si2 : i2;
    bool c3 = mm2 > lm;
    m1 = nm1; i1 = ni1;
    m2 = c3 ? mm2 : lm;
    i2 = c3 ? mi2 : li;
  }
  const float a02t = a02[t];
  const float lse2 = flog2(Z) - 80.0f;
  c2[t] = a02t - lse2;

  const float4* zr4 = (const float4*)(zf + (size_t)t * ED);
  float4 z0 = zr4[0], z1 = zr4[1], z2 = zr4[2], z3 = zr4[3];
  float4 z4 = zr4[4], z5 = zr4[5], z6 = zr4[6], z7 = zr4[7];
  float d1 = dot32x(embn + (size_t)i1 * ED, z0, z1, z2, z3, z4, z5, z6, z7);
  float d2 = dot32x(embn + (size_t)i2 * ED, z0, z1, z2, z3, z4, z5, z6, z7);
  float fb1 = fmaf(K2, d1, a02t + ses2[i1]);
  float fb2 = fmaf(K2, d2, a02t + ses2[i2]);
  int bi = (fb2 > fb1 || (fb2 == fb1 && i2 < i1)) ? i2 : i1;
  idxo[t] = bi;

  // vq sum-of-squares + straight-through output (out = zb + (z_q - zb))
  const int b = t >> 8, hw = t & 255;
  float* ob = out + (size_t)b * (ED * 256) + hw;
  float ss = 0.f;
  const float4* e4 = (const float4*)(embn + (size_t)bi * ED);
#pragma unroll
  for (int j = 0; j < 8; ++j) {
    float4 qv = e4[j];
    float4 zv = (j == 0) ? z0 : (j == 1) ? z1 : (j == 2) ? z2 : (j == 3) ? z3
              : (j == 4) ? z4 : (j == 5) ? z5 : (j == 6) ? z6 : z7;
    float df;
    df = qv.x - zv.x; ss = fmaf(df, df, ss); ob[(4 * j + 0) * 256] = zv.x + (qv.x - zv.x);
    df = qv.y - zv.y; ss = fmaf(df, df, ss); ob[(4 * j + 1) * 256] = zv.y + (qv.y - zv.y);
    df = qv.z - zv.z; ss = fmaf(df, df, ss); ob[(4 * j + 2) * 256] = zv.z + (qv.z - zv.z);
    df = qv.w - zv.w; ss = fmaf(df, df, ss); ob[(4 * j + 3) * 256] = zv.w + (qv.w - zv.w);
  }
  __shared__ float red[256];
  red[threadIdx.x] = ss;
  __syncthreads();
  for (int st = 128; st > 0; st >>= 1) {
    if (threadIdx.x < st) red[threadIdx.x] += red[threadIdx.x + st];
    __syncthreads();
  }
  if (threadIdx.x == 0) atomicAdd(&scal[1], red[0]);
}

// --- pass 2: wave owns 32 codes, sweeps a 1024-row split in 16-row tiles.
//     acc C-init = ses2[code]; dl = acc + c2[t] = fb - lse2 (<=0). ---
__global__ __launch_bounds__(256, 4) void k_pass2(
    const short* __restrict__ ehl, const short* __restrict__ zhl,
    const float* __restrict__ ses2, const float* __restrict__ c2,
    float* __restrict__ avg, float* __restrict__ scal) {
  const int lane = threadIdx.x & 63, wv = threadIdx.x >> 6;
  const int q = lane >> 4, c = lane & 15;
  const int cbase = blockIdx.x * 128 + wv * 32;
  const int tb0 = blockIdx.y * (T / RS2);
  const int NT = (T / RS2) / 16;  // 64

  const s16x8* eg = (const s16x8*)ehl;
  const int atile = cbase >> 4;
  s16x8 ah0 = eg[atile * 128 + lane],       al0 = eg[atile * 128 + 64 + lane];
  s16x8 ah1 = eg[(atile + 1) * 128 + lane], al1 = eg[(atile + 1) * 128 + 64 + lane];

  f32x4 sg0, sg1;
#pragma unroll
  for (int r = 0; r < 4; ++r) {
    sg0[r] = ses2[cbase + q * 4 + r];
    sg1[r] = ses2[cbase + 16 + q * 4 + r];
  }

  float accP[8], accE[8];
#pragma unroll
  for (int k = 0; k < 8; ++k) { accP[k] = 0.f; accE[k] = 0.f; }

  const s16x8* zg = (const s16x8*)zhl;
  const int btile0 = tb0 >> 4;
  s16x8 bh = zg[btile0 * 128 + lane], bl = zg[btile0 * 128 + 64 + lane];
  float cc = c2[tb0 + c];

  for (int tile = 0; tile < NT; ++tile) {
    const int nx = (tile + 1 < NT) ? tile + 1 : tile;
    const int nidx = (btile0 + nx) * 128 + lane;
    s16x8 nh = zg[nidx], nl = zg[nidx + 64];              // prefetch (2x1KB)
    float ncc = c2[tb0 + nx * 16 + c];

    f32x4 acc0 = __builtin_amdgcn_mfma_f32_16x16x32_bf16(ah0, bh, sg0, 0, 0, 0);
    f32x4 acc1 = __builtin_amdgcn_mfma_f32_16x16x32_bf16(ah1, bh, sg1, 0, 0, 0);
    acc0 = __builtin_amdgcn_mfma_f32_16x16x32_bf16(al0, bh, acc0, 0, 0, 0);
    acc1 = __builtin_amdgcn_mfma_f32_16x16x32_bf16(al1, bh, acc1, 0, 0, 0);
    acc0 = __builtin_amdgcn_mfma_f32_16x16x32_bf16(ah0, bl, acc0, 0, 0, 0);
    acc1 = __builtin_amdgcn_mfma_f32_16x16x32_bf16(ah1, bl, acc1, 0, 0, 0);

#pragma unroll
    for (int g = 0; g < 2; ++g) {
#pragma unroll
      for (int r = 0; r < 4; ++r) {
        const int k = g * 4 + r;
        float dl = ((g == 0) ? acc0[r] : acc1[r]) + cc;  // fb - lse2 (<=0)
        float p = fexp2(dl);                              // underflow -> 0
        accP[k] += p;
        accE[k] = fmaf(p, dl, accE[k]);
      }
    }
    bh = nh; bl = nl; cc = ncc;
  }

  float etot = 0.f;
#pragma unroll
  for (int k = 0; k < 8; ++k) etot += accE[k];

#pragma unroll
  for (int d = 1; d < 16; d <<= 1) {
#pragma unroll
    for (int k = 0; k < 8; ++k) accP[k] += __shfl_xor(accP[k], d);
  }
#pragma unroll
  for (int k = 0; k < 8; ++k) {
    if (c == k) {
      const int g = k >> 2, r = k & 3;
      atomicAdd(&avg[cbase + g * 16 + q * 4 + r], accP[k]);
    }
  }
  __shared__ float red[256];
  red[threadIdx.x] = etot;
  __syncthreads();
  for (int st = 128; st > 0; st >>= 1) {
    if (threadIdx.x < st) red[threadIdx.x] += red[threadIdx.x + st];
    __syncthreads();
  }
  if (threadIdx.x == 0) atomicAdd(&scal[0], red[0]);
}

// --- final scalars. ---
__global__ __launch_bounds__(256) void k_final(const float* __restrict__ avg,
    const float* __restrict__ scal, float* __restrict__ out) {
  float s = 0.f;
  for (int i = threadIdx.x; i < N_E; i += 256) {
    float a = avg[i] * (1.0f / T);
    s += a * (flog2(a + 1e-5f) * LN2);
  }
  __shared__ float red[256];
  red[threadIdx.x] = s;
  __syncthreads();
  for (int st = 128; st > 0; st >>= 1) {
    if (threadIdx.x < st) red[threadIdx.x] += red[threadIdx.x + st];
    __syncthreads();
  }
  if (threadIdx.x == 0) {
    float avg_entropy = -red[0];
    float sample_entropy = -(scal[0] * LN2) * (1.0f / T);
    float vq = scal[1] * (1.0f / (T * ED));
    out[T * ED + 0] = vq;
    out[T * ED + 1] = 0.25f * vq;
    out[T * ED + 2] = 0.1f * (sample_entropy - avg_entropy);
  }
}

extern "C" void kernel_launch(void* const* d_in, const int* in_sizes, int n_in,
                              void* d_out, int out_size, void* d_ws, size_t ws_size,
                              hipStream_t stream) {
  const float* z = (const float*)d_in[0];
  const float* emb = (const float*)d_in[1];
  float* out = (float*)d_out;
  float* w = (float*)d_ws;

  float* embn = w;                          // 524288 f
  float* ses2 = embn + 524288;              // 16384
  float* zf   = ses2 + 16384;               // 262144
  float* a02  = zf + 262144;                // 8192
  short* ehl  = (short*)(a02 + 8192);       // 1048576 sh (524288 f)
  short* zhl  = ehl + 1048576;              // 524288 sh  (262144 f)
  float* pm1  = (float*)(zhl + 524288);     // NS1*T = 131072 f
  float* pm2  = pm1 + NS1 * T;              // 131072
  float* pZ   = pm2 + NS1 * T;              // 131072
  int*   pi1  = (int*)(pZ + NS1 * T);       // 131072
  int*   pi2  = pi1 + NS1 * T;              // 131072
  float* c2   = (float*)(pi2 + NS1 * T);    // 8192
  int*   idxo = (int*)(c2 + 8192);          // 8192
  float* avg  = (float*)(idxo + 8192);      // 16384
  float* scal = avg + 16384;                // 2     (~9.1 MB total)

  hipMemsetAsync(avg, 0, (16384 + 2) * sizeof(float), stream);

  k_prep<<<96, 256, 0, stream>>>(emb, z, embn, ses2, zf, a02, ehl, zhl);
  k_pass1<<<dim3(T / 128, NS1), 256, 0, stream>>>(ehl, zhl, ses2, a02,
                                                  pm1, pm2, pZ, pi1, pi2);
  k_merge<<<32, 256, 0, stream>>>(pm1, pm2, pZ, pi1, pi2, zf, embn, ses2, a02,
                                  c2, idxo, scal, out);
  k_pass2<<<dim3(N_E / 128, RS2), 256, 0, stream>>>(ehl, zhl, ses2, c2, avg, scal);
  k_final<<<1, 256, 0, stream>>>(avg, scal, out);
}